// Round 11
// baseline (387.069 us; speedup 1.0000x reference)
//
#include <hip/hip_runtime.h>
#include <hip/hip_fp16.h>
#include <math.h>

#define NUM_GRAPHS 64

typedef unsigned short ushortT;
typedef __attribute__((ext_vector_type(8))) short bf16x8;
typedef __attribute__((ext_vector_type(4))) float f32x4;

// ---- static level tables ----
constexpr int cN[5]       = {20000, 10000, 5000, 2500, 1250};
constexpr int cE[5]       = {320000, 160000, 80000, 40000, 20000};
constexpr int cNOFF[6]    = {0, 20000, 30000, 35000, 37500, 38750};
constexpr int cEOFF[6]    = {0, 320000, 480000, 560000, 600000, 620000};
constexpr int cEBLKOFF[6] = {0, 1250, 1875, 2188, 2345, 2424};
constexpr int cNBLKOFF[6] = {0, 79, 119, 139, 149, 154};
constexpr int cMT[5]      = {5064, 2564, 1314, 689, 377};
constexpr int cTILEOFF[6] = {0, 5064, 7628, 8942, 9631, 10008};
constexpr int cSEOFF[6]   = {0, 324096, 488192, 572288, 616384, 640512};
constexpr int cF1OFF[6]   = {0, 640000, 1280000, 1600000, 1760000, 1840000};
constexpr int cWOFF[6]    = {0, 32000, 96000, 160000, 224000, 288000};
constexpr int cABLK32[6]  = {0, 625, 938, 1095, 1174, 1214};     // ceil(N/32) prefix
constexpr int cRBOFF[5]   = {0, 256, 768, 1280, 1792};           // rootb swizzle uint4 offsets
constexpr int cWAOFF[6]   = {0, 512, 1536, 2560, 3584, 4608};    // Wa swizzle uint4 offsets
constexpr int cRGB[6]     = {0, 313, 470, 549, 589, 609};        // ceil(N/64) prefix
constexpr int cPAIR[6]    = {0, 2532, 3814, 4471, 4816, 5005};   // ceil(cMT/2) prefix

struct P5f { const float* p[5]; };
struct P5i { const int* p[5]; };

__device__ __forceinline__ int lvl_e(int b) {
    return (b >= cEBLKOFF[4]) ? 4 : (b >= cEBLKOFF[3]) ? 3 : (b >= cEBLKOFF[2]) ? 2 : (b >= cEBLKOFF[1]) ? 1 : 0;
}
__device__ __forceinline__ int lvl_n(int b) {
    return (b >= cNBLKOFF[4]) ? 4 : (b >= cNBLKOFF[3]) ? 3 : (b >= cNBLKOFF[2]) ? 2 : (b >= cNBLKOFF[1]) ? 1 : 0;
}

__device__ __forceinline__ ushortT f2bf(float f) {
    union { float f; unsigned int u; } v; v.f = f;
    unsigned int r = (v.u + 0x7FFFu + ((v.u >> 16) & 1u)) >> 16;
    return (ushortT)r;
}
__device__ __forceinline__ float h2f_lo(unsigned int u) {
    return __half2float(__ushort_as_half((ushortT)(u & 0xFFFFu)));
}
__device__ __forceinline__ float h2f_hi(unsigned int u) {
    return __half2float(__ushort_as_half((ushortT)(u >> 16)));
}

// ---- merged: per-block cell histogram + degree count (b<2424) | weight swizzle ------
__global__ void k_hist_wswz(P5f PS, P5i EI, int* __restrict__ dcnt, int* __restrict__ bb,
                            P5f WB, P5f RootB, P5f WA,
                            uint4* __restrict__ hi4, uint4* __restrict__ rb,
                            uint4* __restrict__ wa) {
    int blk = blockIdx.x;
    int t = threadIdx.x;
    if (blk < 2424) {
        int b = blk;
        int l = lvl_e(b);
        int lb = b - cEBLKOFF[l];
        int E = cE[l];
        __shared__ int h[64];
        if (t < 64) h[t] = 0;
        __syncthreads();
        int e = lb * 256 + t;
        if (e < E) {
            atomicAdd(&dcnt[cNOFF[l] + EI.p[l][E + e]], 1);
            const float* ps = PS.p[l];
            int c = (int)floorf(ps[e * 3] * 4.f) * 16 + (int)floorf(ps[e * 3 + 1] * 4.f) * 4
                  + (int)floorf(ps[e * 3 + 2] * 4.f);
            atomicAdd(&h[c], 1);
        }
        __syncthreads();
        if (t < 64) bb[(size_t)b * 64 + t] = h[t];
        return;
    }
    // ---- weight swizzle path (independent of all prep) ----
    int idx = (blk - 2424) * 256 + t;
    if (idx >= 294912) return;
    if (idx < 288000) {
        int l = (idx >= 224000) ? 4 : (idx >= 160000) ? 3 : (idx >= 96000) ? 2 : (idx >= 32000) ? 1 : 0;
        int local = idx - cWOFF[l];
        int T = l ? 2 : 1, C = l ? 64 : 32;
        int lane = local & 63;
        int blk2 = (local >> 6) & 3;
        int rest = local >> 8;
        int st = rest % T, s = rest / T;
        int q = lane >> 4, n = blk2 * 16 + (lane & 15);
        const float* W = WB.p[l];
        union { ushortT u[8]; uint4 v; } ph;
#pragma unroll
        for (int j = 0; j < 8; j++) {
            int k = st * 32 + q * 8 + j;
            ph.u[j] = f2bf(W[((size_t)s * C + k) * 64 + n]);
        }
        hi4[idx] = ph.v;
    } else if (idx < 290304) {
        int id2 = idx - 288000;
        int l = (id2 >= 1792) ? 4 : (id2 >= 1280) ? 3 : (id2 >= 768) ? 2 : (id2 >= 256) ? 1 : 0;
        int local = id2 - cRBOFF[l];
        int lane = local & 63;
        int w = (local >> 6) & 3;
        int st = local >> 8;
        int q = lane >> 4, n = w * 16 + (lane & 15);
        const float* R = RootB.p[l];
        union { ushortT u[8]; uint4 v; } ph;
#pragma unroll
        for (int j = 0; j < 8; j++) {
            int k = st * 32 + q * 8 + j;
            ph.u[j] = f2bf(R[k * 64 + n]);
        }
        rb[id2] = ph.v;
    } else {
        int id3 = idx - 290304;
        int l = (id3 >= cWAOFF[4]) ? 4 : (id3 >= cWAOFF[3]) ? 3 : (id3 >= cWAOFF[2]) ? 2 : (id3 >= cWAOFF[1]) ? 1 : 0;
        int local = id3 - cWAOFF[l];
        int C1 = l ? 64 : 32;
        int numN = C1 / 16;
        int lane = local & 63;
        int rest = local >> 6;       // st*numN + nb
        int nb = rest % numN, st = rest / numN;
        int q = lane >> 4, n = nb * 16 + (lane & 15);
        const float* Wsrc = WA.p[l];
        union { ushortT u[8]; uint4 v; } ph;
#pragma unroll
        for (int j = 0; j < 8; j++) {
            int k = st * 32 + q * 8 + j;
            ph.u[j] = (k < 125) ? f2bf(Wsrc[k * C1 + n]) : (ushortT)0;
        }
        wa[id3] = ph.v;
    }
}

// ---- merged scan phase 1: cell scan (b<80, wave per (l,c)) | node-degree scan -------
__global__ void k_scan1(int* __restrict__ bb_all, int* __restrict__ cellTot,
                        const int* __restrict__ dcnt, int* __restrict__ dbase,
                        int* __restrict__ bsum) {
    int blk = blockIdx.x;
    int t = threadIdx.x;
    if (blk < 80) {
        int W = blk * 4 + (t >> 6);   // 0..319
        int lane = t & 63;
        int l = W >> 6, c = W & 63;
        int* bb = bb_all + (size_t)cEBLKOFF[l] * 64;
        int nblk = cEBLKOFF[l + 1] - cEBLKOFF[l];
        int run = 0;
        for (int b0 = 0; b0 < nblk; b0 += 64) {
            int b = b0 + lane;
            int v = (b < nblk) ? bb[b * 64 + c] : 0;
            int s = v;
#pragma unroll
            for (int off = 1; off < 64; off <<= 1) { int y = __shfl_up(s, off, 64); if (lane >= off) s += y; }
            if (b < nblk) bb[b * 64 + c] = run + s - v;
            run += __shfl(s, 63, 64);
        }
        if (lane == 0) cellTot[l * 64 + c] = run;
        return;
    }
    // ---- node-degree block scan (original k_nscan1) ----
    int b = blk - 80;
    int l = lvl_n(b);
    int lb = b - cNBLKOFF[l];
    int n = cN[l];
    __shared__ int sh[256];
    int i = lb * 256 + t;
    int v = (i < n) ? dcnt[cNOFF[l] + i] : 0;
    sh[t] = v;
    __syncthreads();
    for (int off = 1; off < 256; off <<= 1) {
        int y = (t >= off) ? sh[t - off] : 0;
        __syncthreads();
        sh[t] += y;
        __syncthreads();
    }
    if (i < n) dbase[cNOFF[l] + i] = sh[t] - v;
    if (t == 255) bsum[b] = sh[255];
}

// ---- merged scan phase 2: tile descriptors (b<5) | node block-offset scan -----------
__global__ void k_scan2(const int* __restrict__ cellTot, int* __restrict__ csPad,
                        int* __restrict__ cot_all,
                        const int* __restrict__ bsum, int* __restrict__ boff) {
    int blk = blockIdx.x;
    int t = threadIdx.x;
    if (blk < 5) {
        int l = blk;
        int c = t;
        int tot = cellTot[l * 64 + c];
        int tiles = (tot + 63) >> 6;
        int x = tiles;
#pragma unroll
        for (int off = 1; off < 64; off <<= 1) { int y = __shfl_up(x, off, 64); if (c >= off) x += y; }
        int tileBase = x - tiles;
        csPad[l * 64 + c] = tileBase * 64;
        int* cot = cot_all + cTILEOFF[l];
        for (int i = 0; i < tiles; i++) {
            int vv = tot - (i << 6); if (vv > 64) vv = 64;
            cot[tileBase + i] = c | (vv << 8);      // packed descriptor
        }
        int nT = __shfl(x, 63, 64);
        int mt = cMT[l];
        for (int i = nT + c; i < mt; i += 64) cot[i] = -1;
        return;
    }
    // ---- node block-offset scan (original k_nscan2) ----
    int l = blk - 5;
    int o = cNBLKOFF[l];
    int nb = cNBLKOFF[l + 1] - o;
    int v = (t < nb) ? bsum[o + t] : 0;
    int s = v;
#pragma unroll
    for (int off = 1; off < 64; off <<= 1) { int y = __shfl_up(s, off, 64); if (t >= off) s += y; }
    int tot = __shfl(s, 63, 64);
    if (t < nb) boff[o + t] = s - v;
    int t2 = t + 64;
    int v2 = (t2 < nb) ? bsum[o + t2] : 0;
    int s2 = v2;
#pragma unroll
    for (int off = 1; off < 64; off <<= 1) { int y = __shfl_up(s2, off, 64); if (t >= off) s2 += y; }
    if (t2 < nb) boff[o + t2] = tot + s2 - v2;
}

// ---- merged scatter: one edge pass -> cbrec (cell order, carries posd), darec -------
__global__ void k_scatter(P5f PS, P5i EI, const int* __restrict__ bb, const int* __restrict__ csPad,
                          const int* __restrict__ dbase, const int* __restrict__ boff,
                          int* __restrict__ rank,
                          int4* __restrict__ cbrec, int4* __restrict__ darec) {
    int b = blockIdx.x;
    int l = lvl_e(b);
    int lb = b - cEBLKOFF[l];
    int E = cE[l];
    __shared__ int base[64];
    __shared__ int cnt[64];
    int t = threadIdx.x;
    if (t < 64) { base[t] = bb[(size_t)b * 64 + t] + csPad[l * 64 + t]; cnt[t] = 0; }
    __syncthreads();
    int e = lb * 256 + t;
    if (e >= E) return;
    const float* ps = PS.p[l];
    float v0 = ps[e * 3] * 4.f, v1 = ps[e * 3 + 1] * 4.f, v2 = ps[e * 3 + 2] * 4.f;
    float f0 = floorf(v0), f1v = floorf(v1), f2v = floorf(v2);
    int c = (int)f0 * 16 + (int)f1v * 4 + (int)f2v;
    int r = atomicAdd(&cnt[c], 1);
    int posc = base[c] + r;
    const int* ei = EI.p[l];
    int src = ei[e];
    int dst = ei[E + e];
    int posd = dbase[cNOFF[l] + dst] + boff[cNBLKOFF[l] + (dst >> 8)]
             + atomicAdd(&rank[cNOFF[l] + dst], 1);
    unsigned int fxfy = (unsigned int)__half_as_ushort(__float2half(v0 - f0))
                      | ((unsigned int)__half_as_ushort(__float2half(v1 - f1v)) << 16);
    unsigned int fzp  = (unsigned int)__half_as_ushort(__float2half(v2 - f2v));
    int4 rc;
    rc.x = src; rc.y = posd; rc.z = (int)fxfy; rc.w = (int)fzp;   // posd -> dst-order store
    cbrec[cSEOFF[l] + posc] = rc;
    int4 rd;
    rd.x = src | (dst << 16); rd.y = c; rd.z = (int)fxfy; rd.w = (int)fzp;
    darec[cEOFF[l] + posd] = rd;
}

// ---- Fused Conv A (32-node blocks): pipelined staging, all-wave MFMA tail -----------
__launch_bounds__(256)
__global__ void conv_a_fused(P5f X, P5f RootA, P5f BiasA,
                             const int4* __restrict__ darec, const uint4* __restrict__ wasw,
                             const int* __restrict__ dbase, const int* __restrict__ boff,
                             const int* __restrict__ dcnt, ushortT* __restrict__ f1bf) {
    __shared__ float S[32 * 126];          // 16128 B; Sbf (32x136 bf16) overlaid after convert
    __shared__ int infoS[256];
    __shared__ unsigned int fxyS[256];
    __shared__ unsigned int fzS[256];
    __shared__ float xsS[256];
    int b = blockIdx.x;
    int l = (b >= cABLK32[4]) ? 4 : (b >= cABLK32[3]) ? 3 : (b >= cABLK32[2]) ? 2 : (b >= cABLK32[1]) ? 1 : 0;
    int node0 = (b - cABLK32[l]) * 32;
    int n = cN[l];
    int nn = n - node0; if (nn > 32) nn = 32;
    int t = threadIdx.x;
    int lane = t & 63, wv = t >> 6;
    int C1 = l ? 64 : 32;
    int numN = C1 >> 4;                    // 2 (l0) or 4
    int nTask = 2 * numN;                  // 4 or 8: (node-group g, col-group w')
    // hoist level-constant GEMM B-frags into regs at entry (latency hidden by scatter)
    const uint4* wl = wasw + cWAOFF[l];
    uint4 wfrag0[4], wfrag1[4];
    {
        int w0 = wv % numN;                // task wv  -> g = wv / numN
#pragma unroll
        for (int st = 0; st < 4; st++) wfrag0[st] = wl[(st * numN + w0) * 64 + lane];
        if (nTask == 8) {
            int w1 = wv;                   // task wv+4 -> g = 1, w' = wv (numN==4)
#pragma unroll
            for (int st = 0; st < 4; st++) wfrag1[st] = wl[(st * numN + w1) * 64 + lane];
        }
    }
    for (int i = t; i < 32 * 126; i += 256) S[i] = 0.f;
    const int* db = dbase + cNOFF[l];
    const int* bo = boff + cNBLKOFF[l];
    int estart = db[node0] + bo[node0 >> 8];
    int vend = node0 + nn;
    int eend = (vend >= n) ? cE[l] : (db[vend] + bo[vend >> 8]);
    const float* x = X.p[l];
    const int4* dr = darec + cEOFF[l];
    const int bx = t & 1, by = (t >> 1) & 1, bz = (t >> 2) & 1;
    // prefetch chunk 0 into regs
    int4 rcur; float xcur;
    if (estart + t < eend) { rcur = dr[estart + t]; xcur = x[rcur.x & 0xFFFF]; }
    for (int cs = estart; cs < eend; cs += 256) {
        if (cs + t < eend) {
            infoS[t] = ((((unsigned int)rcur.x) >> 16) - node0) * 64 + rcur.y;
            fxyS[t] = (unsigned int)rcur.z;
            fzS[t] = (unsigned int)rcur.w;
            xsS[t] = xcur;
        }
        __syncthreads();
        // issue next chunk's loads NOW (hidden under this chunk's scatter)
        int pn = cs + 256 + t;
        if (pn < eend) { rcur = dr[pn]; xcur = x[rcur.x & 0xFFFF]; }
        int ne = eend - cs; if (ne > 256) ne = 256;
        for (int j = (t >> 3); j < ne; j += 32) {
            int info = infoS[j];
            int nl = info >> 6, cell = info & 63;
            unsigned int uz = fxyS[j];
            float fx = h2f_lo(uz), fy = h2f_hi(uz), fz = h2f_lo(fzS[j]);
            float xs = xsS[j];
            int cx = cell >> 4, cy = (cell >> 2) & 3, cz = cell & 3;
            int slot = (cx + bx) * 25 + (cy + by) * 5 + (cz + bz);
            float wc = (bx ? fx : 1.f - fx) * (by ? fy : 1.f - fy) * (bz ? fz : 1.f - fz);
            atomicAdd(&S[nl * 126 + slot], wc * xs);
        }
        __syncthreads();
    }
    // in-place convert: S (f32, stride 126) -> Sbf (bf16, stride 136) overlaid on S
    ushortT* Sbf = (ushortT*)S;
    float v[17];
#pragma unroll
    for (int j = 0; j < 17; j++) {
        int i = t + 256 * j;               // i < 4352 = 32*136
        int node = i / 136, k = i % 136;
        v[j] = (i < 4352 && k < 126) ? S[node * 126 + k] : 0.f;
    }
    __syncthreads();
#pragma unroll
    for (int j = 0; j < 17; j++) {
        int i = t + 256 * j;
        if (i < 4352) Sbf[i] = f2bf(v[j]);
    }
    __syncthreads();
    // GEMM tail: all 4 waves active at every level
    int q = lane >> 4, m = lane & 15;
    const int* dcl = dcnt + cNOFF[l];
    ushortT* f1bfl = f1bf + cF1OFF[l];
    auto do_task = [&](int task, const uint4* wf) {
        int g = task / numN;               // node group 0/1
        int w = task - g * numN;           // col group
        f32x4 acc = (f32x4){0.f, 0.f, 0.f, 0.f};
#pragma unroll
        for (int st = 0; st < 4; st++) {
            bf16x8 a = *(const bf16x8*)&Sbf[(16 * g + m) * 136 + st * 32 + q * 8];
            bf16x8 bw = __builtin_bit_cast(bf16x8, wf[st]);
            acc = __builtin_amdgcn_mfma_f32_16x16x32_bf16(a, bw, acc, 0, 0, 0);
        }
        int ch = w * 16 + m;
        float rv = RootA.p[l][ch], bv = BiasA.p[l][ch];
#pragma unroll
        for (int rr = 0; rr < 4; rr++) {
            int row = 16 * g + q * 4 + rr;
            if (row < nn) {
                int gnode = node0 + row;
                int dv = dcl[gnode];
                float d = (float)(dv > 1 ? dv : 1);
                float o = acc[rr] / d + x[gnode] * rv + bv;
                f1bfl[(size_t)gnode * C1 + ch] = f2bf(fmaxf(o, 0.f));
            }
        }
    };
    do_task(wv, wfrag0);                   // l0: tasks 0..3; l>0: tasks 0..3 then 4..7
    if (nTask == 8) do_task(wv + 4, wfrag1);
}

// ---- async A-tile stage: global f1bf rows -> LDS, source-side XOR swizzle -----------
// slot(row,chunk) = row*NC + (chunk ^ (row & (NC-1))); LDS dest is linear (m104).
template<int CIN>
__device__ __forceinline__ void stage_issue(const ushortT* __restrict__ f1bfl, int srcx,
                                            ushortT* lregion, int lane) {
    const int NC = CIN / 8;               // 16B chunks per row
#pragma unroll
    for (int i = 0; i < NC; i++) {        // NC issues of 64 lanes x 16B
        int s = i * 64 + lane;
        int row = s / NC;
        int cp = s & (NC - 1);
        int chunk = cp ^ (row & (NC - 1));
        int src = __shfl(srcx, row, 64);
        const ushortT* gp = f1bfl + (size_t)src * CIN + chunk * 8;
        __builtin_amdgcn_global_load_lds(
            (const __attribute__((address_space(1))) void*)gp,
            (__attribute__((address_space(3))) void*)(lregion + (size_t)i * 512),
            16, 0, 0);
    }
}

// ---- read staged A-frags (same XOR) -> registers ------------------------------------
template<int CIN>
__device__ __forceinline__ void read_ahr(const ushortT* st, bf16x8 (&ahr)[4][CIN / 32],
                                         int q, int m) {
    const int NC = CIN / 8;
#pragma unroll
    for (int mt = 0; mt < 4; mt++) {
        int row = 16 * mt + m;
#pragma unroll
        for (int s = 0; s < CIN / 32; s++) {
            int chunk = s * 4 + q;
            int cp = chunk ^ (row & (NC - 1));
            ahr[mt][s] = *(const bf16x8*)&st[(size_t)row * NC * 8 + cp * 8];
        }
    }
}

// ---- Conv B tile compute: MFMA -> LDS tile assembly -> full-line dst-order store ----
template<int CIN>
__device__ __forceinline__ void conv_b_tile_compute(
    const uint4* __restrict__ whiL, __half* __restrict__ pout,
    bf16x8 (&ahr)[4][CIN / 32], const float* __restrict__ wxy,
    const float* __restrict__ fzp, const int* __restrict__ pd, int valid,
    int cell, int lane, int wv, __half* __restrict__ outS) {
    const int T = CIN / 32;
    int q = lane >> 4, m = lane & 15;
    int cx = cell >> 4, cy = (cell >> 2) & 3, cz = cell & 3;
    float fzr[16];
#pragma unroll
    for (int mt = 0; mt < 4; mt++)
#pragma unroll
        for (int rr = 0; rr < 4; rr++)
            fzr[mt * 4 + rr] = fzp[16 * mt + q * 4 + rr];

    uint4 wb[2][2 * T];
    auto loadw = [&](int xy, uint4* dst) {
        int bx = xy & 1, by = xy >> 1;
        int s0 = (cx + bx) * 25 + (cy + by) * 5 + cz;
#pragma unroll
        for (int st = 0; st < T; st++) {
            dst[st]     = whiL[((size_t)(s0 * T + st) * 4 + wv) * 64 + lane];
            dst[T + st] = whiL[((size_t)((s0 + 1) * T + st) * 4 + wv) * 64 + lane];
        }
    };
    loadw(0, wb[0]);

    f32x4 acc[4];
#pragma unroll
    for (int mt = 0; mt < 4; mt++) acc[mt] = (f32x4){0.f, 0.f, 0.f, 0.f};

#pragma unroll
    for (int xy = 0; xy < 4; xy++) {
        uint4* cur = wb[xy & 1];
        if (xy < 3) loadw(xy + 1, wb[(xy + 1) & 1]);
        f32x4 C0[4], C1[4];
#pragma unroll
        for (int mt = 0; mt < 4; mt++) {
            C0[mt] = (f32x4){0.f, 0.f, 0.f, 0.f};
            C1[mt] = (f32x4){0.f, 0.f, 0.f, 0.f};
        }
#pragma unroll
        for (int st = 0; st < T; st++) {
            bf16x8 b0 = __builtin_bit_cast(bf16x8, cur[st]);
            bf16x8 b1 = __builtin_bit_cast(bf16x8, cur[T + st]);
#pragma unroll
            for (int mt = 0; mt < 4; mt++) {
                C0[mt] = __builtin_amdgcn_mfma_f32_16x16x32_bf16(ahr[mt][st], b0, C0[mt], 0, 0, 0);
                C1[mt] = __builtin_amdgcn_mfma_f32_16x16x32_bf16(ahr[mt][st], b1, C1[mt], 0, 0, 0);
            }
        }
        const float* wrow = &wxy[xy * 64];
#pragma unroll
        for (int mt = 0; mt < 4; mt++)
#pragma unroll
            for (int rr = 0; rr < 4; rr++) {
                float wxyv = wrow[16 * mt + q * 4 + rr];   // LDS broadcast (4 addrs/wave)
                float dlt = C1[mt][rr] - C0[mt][rr];
                float tt = fmaf(fzr[mt * 4 + rr], dlt, C0[mt][rr]);
                acc[mt][rr] = fmaf(wxyv, tt, acc[mt][rr]);
            }
    }
    // assemble output tile in LDS (wave writes its 16-col slice)
#pragma unroll
    for (int mt = 0; mt < 4; mt++)
#pragma unroll
        for (int rr = 0; rr < 4; rr++) {
            int row = 16 * mt + q * 4 + rr;
            outS[row * 68 + 16 * wv + m] = __float2half(acc[mt][rr]);
        }
    __syncthreads();
    // cooperative full-line scatter: 8 lanes x 16B = one 128B row at pd[row]
    int t = (wv << 6) | lane;
#pragma unroll
    for (int p = 0; p < 2; p++) {
        int row = p * 32 + (t >> 3);
        int part = t & 7;
        if (row < valid) {
            uint4 vv = *(const uint4*)&outS[row * 68 + part * 8];
            *(uint4*)&pout[(size_t)pd[row] * 64 + part * 8] = vv;
        }
    }
    __syncthreads();   // outS reusable for next tile
}

// ---- conv B pair: tile1's cbrec+A staged async to LDS under tile0's compute ---------
template<int CIN>
__device__ __forceinline__ void conv_b_pair(
    const ushortT* __restrict__ f1bfl, const int4* __restrict__ cbl,
    const uint4* __restrict__ whiL, __half* __restrict__ pout,
    int d0, int d1, int tb0, int tb1, int lane, int wv,
    ushortT* stage0, ushortT* stage1, __half* __restrict__ outS,
    float* __restrict__ wxy0, float* __restrict__ fz0, int* __restrict__ pd0,
    float* __restrict__ wxy1, float* __restrict__ fz1, int* __restrict__ pd1) {
    const int T = CIN / 32;
    int q = lane >> 4, m = lane & 15;
    bool has1 = d1 >= 0;
    int cell0 = d0 & 63, v0 = d0 >> 8;
    int cell1 = has1 ? (d1 & 63) : 0, v1 = has1 ? (d1 >> 8) : 0;

    int4 r0, r1;
    if (lane < v0) r0 = cbl[tb0 + lane]; else { r0.x = 0; r0.y = 0; r0.z = 0; r0.w = 0; }
    if (lane < v1) r1 = cbl[tb1 + lane]; else { r1.x = 0; r1.y = 0; r1.z = 0; r1.w = 0; }

    {
        unsigned int uz = (unsigned int)r0.z;
        float fx = h2f_lo(uz), fy = h2f_hi(uz);
        float gx = 1.f - fx, gy = 1.f - fy;
        wxy0[0 * 64 + lane] = gx * gy;
        wxy0[1 * 64 + lane] = fx * gy;
        wxy0[2 * 64 + lane] = gx * fy;
        wxy0[3 * 64 + lane] = fx * fy;
        fz0[lane] = h2f_lo((unsigned int)r0.w);
        pd0[lane] = r0.y;
    }
    {
        unsigned int uz = (unsigned int)r1.z;
        float fx = h2f_lo(uz), fy = h2f_hi(uz);
        float gx = 1.f - fx, gy = 1.f - fy;
        wxy1[0 * 64 + lane] = gx * gy;
        wxy1[1 * 64 + lane] = fx * gy;
        wxy1[2 * 64 + lane] = gx * fy;
        wxy1[3 * 64 + lane] = fx * fy;
        fz1[lane] = h2f_lo((unsigned int)r1.w);
        pd1[lane] = r1.y;
    }
    __builtin_amdgcn_wave_barrier();   // pin LDS write->read order (same-wave DS in-order)

    // issue both A stages (async, zero VGPR); waves duplicate same-value writes (benign)
    stage_issue<CIN>(f1bfl, r0.x, stage0, lane);
    if (has1) stage_issue<CIN>(f1bfl, r1.x, stage1, lane);

    // wait only for stage0 (tile1's NC loads stay in flight across tile0's compute)
    if (has1) {
        if (CIN == 64) asm volatile("s_waitcnt vmcnt(8)" ::: "memory");
        else           asm volatile("s_waitcnt vmcnt(4)" ::: "memory");
    } else {
        asm volatile("s_waitcnt vmcnt(0)" ::: "memory");
    }

    bf16x8 ahr[4][T];
    read_ahr<CIN>(stage0, ahr, q, m);
    conv_b_tile_compute<CIN>(whiL, pout, ahr, wxy0, fz0, pd0, v0, cell0, lane, wv, outS);

    if (has1) {
        asm volatile("s_waitcnt vmcnt(0)" ::: "memory");
        read_ahr<CIN>(stage1, ahr, q, m);
        conv_b_tile_compute<CIN>(whiL, pout, ahr, wxy1, fz1, pd1, v1, cell1, lane, wv, outS);
    }
}

// ---- merged: rgemm (b<609) | conv B tile pairs — independent outputs f2 / Ph --------
__launch_bounds__(256, 2)
__global__ void conv_brg(const ushortT* __restrict__ f1bf, const int4* __restrict__ cbrec,
                         const uint4* __restrict__ whi, const int* __restrict__ cot,
                         __half* __restrict__ Ph,
                         const uint4* __restrict__ rb, float* __restrict__ f2) {
    __shared__ __align__(16) ushortT stageS[2][4096];  // 2 tiles x 8KB (worst CIN=64)
    __shared__ __align__(16) __half outS[64 * 68];     // 8704B output assembly tile
    __shared__ float wxyS[2][256];
    __shared__ float fzS[2][64];
    __shared__ int pdS[2][64];
    int t = threadIdx.x;
    int wv = t >> 6, lane = t & 63;
    int blk = blockIdx.x;
    if (blk < 609) {
        // ---- R-gemm: f2 = f1bf @ rootb (independent of conv_b; overlaps it) ----
        int b = blk;
        int l = (b >= cRGB[4]) ? 4 : (b >= cRGB[3]) ? 3 : (b >= cRGB[2]) ? 2 : (b >= cRGB[1]) ? 1 : 0;
        int node0 = (b - cRGB[l]) * 64;
        int n = cN[l];
        int nn = n - node0; if (nn > 64) nn = 64;
        int q = lane >> 4, m = lane & 15;
        const int CIN = l ? 64 : 32;
        const int T = l ? 2 : 1;
        const ushortT* fl = f1bf + cF1OFF[l];
        const uint4* rbl = rb + cRBOFF[l];
        f32x4 C[4];
#pragma unroll
        for (int mt = 0; mt < 4; mt++) C[mt] = (f32x4){0.f, 0.f, 0.f, 0.f};
        for (int st = 0; st < T; st++) {
            bf16x8 bh = __builtin_bit_cast(bf16x8, rbl[(st * 4 + wv) * 64 + lane]);
#pragma unroll
            for (int mt = 0; mt < 4; mt++) {
                int row = 16 * mt + m;
                int nr = node0 + row; if (nr > n - 1) nr = n - 1;
                bf16x8 a = *(const bf16x8*)&fl[(size_t)nr * CIN + st * 32 + q * 8];
                C[mt] = __builtin_amdgcn_mfma_f32_16x16x32_bf16(a, bh, C[mt], 0, 0, 0);
            }
        }
#pragma unroll
        for (int mt = 0; mt < 4; mt++)
#pragma unroll
            for (int rr = 0; rr < 4; rr++) {
                int row = 16 * mt + q * 4 + rr;
                if (row < nn)
                    f2[(size_t)(cNOFF[l] + node0 + row) * 64 + 16 * wv + m] = C[mt][rr];
            }
        return;
    }
    // ---- conv B pair path ----
    int b = blk - 609;
    int l = (b >= cPAIR[4]) ? 4 : (b >= cPAIR[3]) ? 3 : (b >= cPAIR[2]) ? 2 : (b >= cPAIR[1]) ? 1 : 0;
    int p = b - cPAIR[l];
    int t0 = 2 * p, t1 = t0 + 1;
    const int* cotl = cot + cTILEOFF[l];
    int d0 = cotl[t0];
    int d1 = (t1 < cMT[l]) ? cotl[t1] : -1;
    if (d0 < 0) return;                    // block-uniform
    int tb0 = t0 * 64, tb1 = t1 * 64;
    if (l == 0)
        conv_b_pair<32>(f1bf, cbrec, whi, Ph, d0, d1, tb0, tb1, lane, wv,
                        stageS[0], stageS[1], outS,
                        wxyS[0], fzS[0], pdS[0], wxyS[1], fzS[1], pdS[1]);
    else
        conv_b_pair<64>(f1bf + cF1OFF[l], cbrec + cSEOFF[l], whi + cWOFF[l],
                        Ph + (size_t)cEOFF[l] * 64, d0, d1, tb0, tb1, lane, wv,
                        stageS[0], stageS[1], outS,
                        wxyS[0], fzS[0], pdS[0], wxyS[1], fzS[1], pdS[1]);
}

// ---- fused node epilogue + readout: 8-node windows, VECTORIZED Ph stream ------------
// uint2/lane = 8B: one wave-load covers 4 rows x 64ch. Lane L accumulates channels
// 4*(L&15)..+3 for row-parity L>>4; node-end merge = shfl_xor(16)+shfl_xor(32).
// Run-boundary atomics only (R9 lesson); lanes<16 issue 4 consecutive-addr adds.
__launch_bounds__(256)
__global__ void node_read(const __half* __restrict__ Ph,
                          const int* __restrict__ dbase, const int* __restrict__ boff,
                          const int* __restrict__ dcnt, P5f BiasB, P5i Batch,
                          const float* __restrict__ f2,
                          float* __restrict__ hsum, float* __restrict__ gcnt) {
    const int RC[6] = {0, 2500, 3750, 4375, 4688, 4845};   // ceil(N/8) prefix
    int t = threadIdx.x;
    int lane = t & 63;
    int w = blockIdx.x * 4 + (t >> 6);
    if (w >= 4845) return;
    int l = (w >= RC[4]) ? 4 : (w >= RC[3]) ? 3 : (w >= RC[2]) ? 2 : (w >= RC[1]) ? 1 : 0;
    int base = (w - RC[l]) * 8;
    int Nl = cN[l];
    int nn = Nl - base; if (nn > 8) nn = 8;
    const __half* PhL = Ph + (size_t)cEOFF[l] * 64;
    const float* f2b = f2 + (size_t)(cNOFF[l] + base) * 64;
    int c4 = (lane & 15) * 4;              // this lane's channel quad
    int rp = lane >> 4;                    // row parity 0..3
    float4 bias4 = *(const float4*)&BiasB.p[l][c4];
    // lane-parallel metadata load for the window's 8 nodes, broadcast via shfl
    int myStart = 0, myDeg = 0, myG = 0;
    if (lane < nn) {
        int node = base + lane;
        myStart = dbase[cNOFF[l] + node] + boff[cNBLKOFF[l] + (node >> 8)];
        myDeg = dcnt[cNOFF[l] + node];
        myG = Batch.p[l][node];
    }
    int curg = -1;
    float h0 = 0.f, h1 = 0.f, h2 = 0.f, h3 = 0.f;   // run accumulator (channel quad)
    int crun = 0;
    for (int j = 0; j < nn; j++) {
        int start = __shfl(myStart, j, 64);
        int deg = __shfl(myDeg, j, 64);
        int g = __shfl(myG, j, 64);
        float a0 = 0.f, a1 = 0.f, a2 = 0.f, a3 = 0.f;
        int k = 0;
        for (; k + 4 <= deg; k += 4) {      // 4 rows = 512B per wave-load
            uint2 v = *(const uint2*)(PhL + (size_t)(start + k) * 64 + lane * 4);
            a0 += h2f_lo(v.x); a1 += h2f_hi(v.x);
            a2 += h2f_lo(v.y); a3 += h2f_hi(v.y);
        }
        if (k < deg && k + rp < deg) {      // tail rows, same lane->channel mapping
            uint2 v = *(const uint2*)(PhL + (size_t)(start + k) * 64 + lane * 4);
            a0 += h2f_lo(v.x); a1 += h2f_hi(v.x);
            a2 += h2f_lo(v.y); a3 += h2f_hi(v.y);
        }
        // merge the 4 row-parities: lanes L, L^16, L^32, L^48 share a channel quad
        a0 += __shfl_xor(a0, 16, 64); a1 += __shfl_xor(a1, 16, 64);
        a2 += __shfl_xor(a2, 16, 64); a3 += __shfl_xor(a3, 16, 64);
        a0 += __shfl_xor(a0, 32, 64); a1 += __shfl_xor(a1, 32, 64);
        a2 += __shfl_xor(a2, 32, 64); a3 += __shfl_xor(a3, 32, 64);
        float dinv = 1.f / (float)(deg > 1 ? deg : 1);
        float4 fr = *(const float4*)&f2b[(size_t)j * 64 + c4];
        float s0 = fmaxf(a0 * dinv + fr.x + bias4.x, 0.f);
        float s1 = fmaxf(a1 * dinv + fr.y + bias4.y, 0.f);
        float s2 = fmaxf(a2 * dinv + fr.z + bias4.z, 0.f);
        float s3 = fmaxf(a3 * dinv + fr.w + bias4.w, 0.f);
        if (g != curg) {
            if (curg >= 0) {
                if (lane < 16) {
                    float* hp = &hsum[curg * 320 + l * 64 + c4];
                    atomicAdd(hp + 0, h0); atomicAdd(hp + 1, h1);
                    atomicAdd(hp + 2, h2); atomicAdd(hp + 3, h3);
                }
                if (lane == 0) atomicAdd(&gcnt[l * 64 + curg], (float)crun);
            }
            curg = g; h0 = h1 = h2 = h3 = 0.f; crun = 0;
        }
        h0 += s0; h1 += s1; h2 += s2; h3 += s3;
        crun++;
    }
    if (curg >= 0) {
        if (lane < 16) {
            float* hp = &hsum[curg * 320 + l * 64 + c4];
            atomicAdd(hp + 0, h0); atomicAdd(hp + 1, h1);
            atomicAdd(hp + 2, h2); atomicAdd(hp + 3, h3);
        }
        if (lane == 0) atomicAdd(&gcnt[l * 64 + curg], (float)crun);
    }
}

// ---------------- FC + log_softmax: one block per graph ----------------
__global__ void fc_kernel(const float* __restrict__ hsum, const float* __restrict__ gcnt,
                          const float* __restrict__ fcw, const float* __restrict__ fcb,
                          float* __restrict__ out) {
    int g = blockIdx.x;
    int lane = threadIdx.x;  // 64
    float partial[10];
#pragma unroll
    for (int t = 0; t < 10; t++) partial[t] = 0.f;
#pragma unroll
    for (int k = 0; k < 5; k++) {
        int j = k * 64 + lane;
        float c = fmaxf(gcnt[k * 64 + g], 1.f);
        float h = hsum[g * 320 + j] / c;
        const float* fw = fcw + j * 10;
#pragma unroll
        for (int t = 0; t < 10; t++) partial[t] = fmaf(h, fw[t], partial[t]);
    }
#pragma unroll
    for (int off = 32; off >= 1; off >>= 1)
#pragma unroll
        for (int t = 0; t < 10; t++) partial[t] += __shfl_xor(partial[t], off, 64);
    if (lane == 0) {
        float logit[10];
#pragma unroll
        for (int t = 0; t < 10; t++) logit[t] = partial[t] + fcb[t];
        float m = logit[0];
#pragma unroll
        for (int t = 1; t < 10; t++) m = fmaxf(m, logit[t]);
        float sum = 0.f;
#pragma unroll
        for (int t = 0; t < 10; t++) sum += expf(logit[t] - m);
        float lse = m + logf(sum);
#pragma unroll
        for (int t = 0; t < 10; t++) out[g * 10 + t] = logit[t] - lse;
    }
}

extern "C" void kernel_launch(void* const* d_in, const int* in_sizes, int n_in,
                              void* d_out, int out_size, void* d_ws, size_t ws_size,
                              hipStream_t stream) {
    int* wsI = (int*)d_ws;
    int*   dcnt  = wsI;                          // 38750
    int*   rank  = dcnt + 38750;                 // 38750
    float* hsum  = (float*)(rank + 38750);       // 20480  (hsum[g*320 + l*64 + lane])
    float* gcnt  = hsum + 20480;                 // 320
    float* f2    = gcnt + 320;                   // 2,480,000 (R from rgemm; read-only in node_read)
    int*   dbase = (int*)(f2 + 2480000);         // 38750
    int*   bsum  = dbase + 38750;                // 160
    int*   boff  = bsum + 160;                   // 160
    int*   cpos  = boff + 160;                   // 620000 (unused after dst-order Ph)
    int*   bb    = cpos + 620000;                // 155136
    int*   csPad = bb + 155136;                  // 320
    int*   cellTot = csPad + 320;                // 320
    int*   cot   = cellTot + 320;                // 10008
    int4*  cbrec = (int4*)(((size_t)(cot + 10008) + 15) & ~(size_t)15);   // 640512 recs
    int4*  darec = cbrec + 640512;               // 620000 recs
    ushortT* f1bf = (ushortT*)(darec + 620000);  // 1,840,000 ushorts
    uint4* whi   = (uint4*)(((size_t)(f1bf + 1840000) + 15) & ~(size_t)15);  // 288000
    uint4* rbsw  = whi + 288000;                 // 2304
    uint4* wasw  = rbsw + 2304;                  // 4608
    __half* Ph   = (__half*)(wasw + 4608);       // 620000 rows of 64 (dst-ordered per level)

    hipMemsetAsync(dcnt, 0, (size_t)(38750 * 2 + 20480 + 320) * sizeof(int), stream);

    P5f PS, X, WA, RootA, BiasA, WB, RootB, BiasB;
    P5i EI, Batch;
    for (int l = 0; l < 5; l++) {
        const int b = l * 10;
        X.p[l]     = (const float*)d_in[b + 0];
        PS.p[l]    = (const float*)d_in[b + 1];
        EI.p[l]    = (const int*)d_in[b + 2];
        Batch.p[l] = (const int*)d_in[b + 3];
        WA.p[l]    = (const float*)d_in[b + 4];
        RootA.p[l] = (const float*)d_in[b + 5];
        BiasA.p[l] = (const float*)d_in[b + 6];
        WB.p[l]    = (const float*)d_in[b + 7];
        RootB.p[l] = (const float*)d_in[b + 8];
        BiasB.p[l] = (const float*)d_in[b + 9];
    }

    // prep: hist + weight-swizzle fused (wswz independent, hides under hist)
    k_hist_wswz<<<3576, 256, 0, stream>>>(PS, EI, dcnt, bb, WB, RootB, WA,
                                          whi, rbsw, wasw);
    k_scan1<<<234, 256, 0, stream>>>(bb, cellTot, dcnt, dbase, bsum);
    k_scan2<<<10, 64, 0, stream>>>(cellTot, csPad, cot, bsum, boff);
    k_scatter<<<2424, 256, 0, stream>>>(PS, EI, bb, csPad, dbase, boff, rank,
                                        cbrec, darec);

    // conv A (all levels, 32-node blocks, pipelined staging) -> f1bf
    conv_a_fused<<<1214, 256, 0, stream>>>(X, RootA, BiasA, darec, wasw,
                                           dbase, boff, dcnt, f1bf);

    // rgemm + conv B fused (independent outputs f2 / Ph; rgemm hides under conv_b)
    conv_brg<<<5614, 256, 0, stream>>>(f1bf, cbrec, whi, cot, Ph, rbsw, f2);

    // fused node epilogue + readout: vectorized Ph stream -> run-accumulated atomics
    node_read<<<1212, 256, 0, stream>>>(Ph, dbase, boff, dcnt, BiasB, Batch, f2,
                                        hsum, gcnt);

    // FC + log_softmax
    fc_kernel<<<64, 64, 0, stream>>>(hsum, gcnt, (const float*)d_in[50], (const float*)d_in[51],
                                     (float*)d_out);
}

// Round 12
// 377.793 us; speedup vs baseline: 1.0246x; 1.0246x over previous
//
#include <hip/hip_runtime.h>
#include <hip/hip_fp16.h>
#include <math.h>

#define NUM_GRAPHS 64

typedef unsigned short ushortT;
typedef __attribute__((ext_vector_type(8))) short bf16x8;
typedef __attribute__((ext_vector_type(4))) float f32x4;

// ---- static level tables ----
constexpr int cN[5]       = {20000, 10000, 5000, 2500, 1250};
constexpr int cE[5]       = {320000, 160000, 80000, 40000, 20000};
constexpr int cNOFF[6]    = {0, 20000, 30000, 35000, 37500, 38750};
constexpr int cEOFF[6]    = {0, 320000, 480000, 560000, 600000, 620000};
constexpr int cEBLKOFF[6] = {0, 1250, 1875, 2188, 2345, 2424};
constexpr int cNBLKOFF[6] = {0, 79, 119, 139, 149, 154};
constexpr int cMT[5]      = {5064, 2564, 1314, 689, 377};
constexpr int cTILEOFF[6] = {0, 5064, 7628, 8942, 9631, 10008};
constexpr int cSEOFF[6]   = {0, 324096, 488192, 572288, 616384, 640512};
constexpr int cF1OFF[6]   = {0, 640000, 1280000, 1600000, 1760000, 1840000};
constexpr int cWOFF[6]    = {0, 32000, 96000, 160000, 224000, 288000};
constexpr int cABLK32[6]  = {0, 625, 938, 1095, 1174, 1214};     // ceil(N/32) prefix
constexpr int cRBOFF[5]   = {0, 256, 768, 1280, 1792};           // rootb swizzle uint4 offsets
constexpr int cWAOFF[6]   = {0, 512, 1536, 2560, 3584, 4608};    // Wa swizzle uint4 offsets
constexpr int cRGB[6]     = {0, 313, 470, 549, 589, 609};        // ceil(N/64) prefix
constexpr int cPAIR[6]    = {0, 2532, 3814, 4471, 4816, 5005};   // ceil(cMT/2) prefix

struct P5f { const float* p[5]; };
struct P5i { const int* p[5]; };

__device__ __forceinline__ int lvl_e(int b) {
    return (b >= cEBLKOFF[4]) ? 4 : (b >= cEBLKOFF[3]) ? 3 : (b >= cEBLKOFF[2]) ? 2 : (b >= cEBLKOFF[1]) ? 1 : 0;
}
__device__ __forceinline__ int lvl_n(int b) {
    return (b >= cNBLKOFF[4]) ? 4 : (b >= cNBLKOFF[3]) ? 3 : (b >= cNBLKOFF[2]) ? 2 : (b >= cNBLKOFF[1]) ? 1 : 0;
}

__device__ __forceinline__ ushortT f2bf(float f) {
    union { float f; unsigned int u; } v; v.f = f;
    unsigned int r = (v.u + 0x7FFFu + ((v.u >> 16) & 1u)) >> 16;
    return (ushortT)r;
}
__device__ __forceinline__ float h2f_lo(unsigned int u) {
    return __half2float(__ushort_as_half((ushortT)(u & 0xFFFFu)));
}
__device__ __forceinline__ float h2f_hi(unsigned int u) {
    return __half2float(__ushort_as_half((ushortT)(u >> 16)));
}

// ---- merged: per-block cell histogram + degree count (b<2424) | weight swizzle ------
__global__ void k_hist_wswz(P5f PS, P5i EI, int* __restrict__ dcnt, int* __restrict__ bb,
                            P5f WB, P5f RootB, P5f WA,
                            uint4* __restrict__ hi4, uint4* __restrict__ rb,
                            uint4* __restrict__ wa) {
    int blk = blockIdx.x;
    int t = threadIdx.x;
    if (blk < 2424) {
        int b = blk;
        int l = lvl_e(b);
        int lb = b - cEBLKOFF[l];
        int E = cE[l];
        __shared__ int h[64];
        if (t < 64) h[t] = 0;
        __syncthreads();
        int e = lb * 256 + t;
        if (e < E) {
            atomicAdd(&dcnt[cNOFF[l] + EI.p[l][E + e]], 1);
            const float* ps = PS.p[l];
            int c = (int)floorf(ps[e * 3] * 4.f) * 16 + (int)floorf(ps[e * 3 + 1] * 4.f) * 4
                  + (int)floorf(ps[e * 3 + 2] * 4.f);
            atomicAdd(&h[c], 1);
        }
        __syncthreads();
        if (t < 64) bb[(size_t)b * 64 + t] = h[t];
        return;
    }
    // ---- weight swizzle path (independent of all prep) ----
    int idx = (blk - 2424) * 256 + t;
    if (idx >= 294912) return;
    if (idx < 288000) {
        int l = (idx >= 224000) ? 4 : (idx >= 160000) ? 3 : (idx >= 96000) ? 2 : (idx >= 32000) ? 1 : 0;
        int local = idx - cWOFF[l];
        int T = l ? 2 : 1, C = l ? 64 : 32;
        int lane = local & 63;
        int blk2 = (local >> 6) & 3;
        int rest = local >> 8;
        int st = rest % T, s = rest / T;
        int q = lane >> 4, n = blk2 * 16 + (lane & 15);
        const float* W = WB.p[l];
        union { ushortT u[8]; uint4 v; } ph;
#pragma unroll
        for (int j = 0; j < 8; j++) {
            int k = st * 32 + q * 8 + j;
            ph.u[j] = f2bf(W[((size_t)s * C + k) * 64 + n]);
        }
        hi4[idx] = ph.v;
    } else if (idx < 290304) {
        int id2 = idx - 288000;
        int l = (id2 >= 1792) ? 4 : (id2 >= 1280) ? 3 : (id2 >= 768) ? 2 : (id2 >= 256) ? 1 : 0;
        int local = id2 - cRBOFF[l];
        int lane = local & 63;
        int w = (local >> 6) & 3;
        int st = local >> 8;
        int q = lane >> 4, n = w * 16 + (lane & 15);
        const float* R = RootB.p[l];
        union { ushortT u[8]; uint4 v; } ph;
#pragma unroll
        for (int j = 0; j < 8; j++) {
            int k = st * 32 + q * 8 + j;
            ph.u[j] = f2bf(R[k * 64 + n]);
        }
        rb[id2] = ph.v;
    } else {
        int id3 = idx - 290304;
        int l = (id3 >= cWAOFF[4]) ? 4 : (id3 >= cWAOFF[3]) ? 3 : (id3 >= cWAOFF[2]) ? 2 : (id3 >= cWAOFF[1]) ? 1 : 0;
        int local = id3 - cWAOFF[l];
        int C1 = l ? 64 : 32;
        int numN = C1 / 16;
        int lane = local & 63;
        int rest = local >> 6;       // st*numN + nb
        int nb = rest % numN, st = rest / numN;
        int q = lane >> 4, n = nb * 16 + (lane & 15);
        const float* Wsrc = WA.p[l];
        union { ushortT u[8]; uint4 v; } ph;
#pragma unroll
        for (int j = 0; j < 8; j++) {
            int k = st * 32 + q * 8 + j;
            ph.u[j] = (k < 125) ? f2bf(Wsrc[k * C1 + n]) : (ushortT)0;
        }
        wa[id3] = ph.v;
    }
}

// ---- merged scan phase 1: cell scan (b<80, wave per (l,c)) | node-degree scan -------
__global__ void k_scan1(int* __restrict__ bb_all, int* __restrict__ cellTot,
                        const int* __restrict__ dcnt, int* __restrict__ dbase,
                        int* __restrict__ bsum) {
    int blk = blockIdx.x;
    int t = threadIdx.x;
    if (blk < 80) {
        int W = blk * 4 + (t >> 6);   // 0..319
        int lane = t & 63;
        int l = W >> 6, c = W & 63;
        int* bb = bb_all + (size_t)cEBLKOFF[l] * 64;
        int nblk = cEBLKOFF[l + 1] - cEBLKOFF[l];
        int run = 0;
        for (int b0 = 0; b0 < nblk; b0 += 64) {
            int b = b0 + lane;
            int v = (b < nblk) ? bb[b * 64 + c] : 0;
            int s = v;
#pragma unroll
            for (int off = 1; off < 64; off <<= 1) { int y = __shfl_up(s, off, 64); if (lane >= off) s += y; }
            if (b < nblk) bb[b * 64 + c] = run + s - v;
            run += __shfl(s, 63, 64);
        }
        if (lane == 0) cellTot[l * 64 + c] = run;
        return;
    }
    // ---- node-degree block scan (original k_nscan1) ----
    int b = blk - 80;
    int l = lvl_n(b);
    int lb = b - cNBLKOFF[l];
    int n = cN[l];
    __shared__ int sh[256];
    int i = lb * 256 + t;
    int v = (i < n) ? dcnt[cNOFF[l] + i] : 0;
    sh[t] = v;
    __syncthreads();
    for (int off = 1; off < 256; off <<= 1) {
        int y = (t >= off) ? sh[t - off] : 0;
        __syncthreads();
        sh[t] += y;
        __syncthreads();
    }
    if (i < n) dbase[cNOFF[l] + i] = sh[t] - v;
    if (t == 255) bsum[b] = sh[255];
}

// ---- merged scan phase 2: tile descriptors (b<5) | node block-offset scan -----------
__global__ void k_scan2(const int* __restrict__ cellTot, int* __restrict__ csPad,
                        int* __restrict__ cot_all,
                        const int* __restrict__ bsum, int* __restrict__ boff) {
    int blk = blockIdx.x;
    int t = threadIdx.x;
    if (blk < 5) {
        int l = blk;
        int c = t;
        int tot = cellTot[l * 64 + c];
        int tiles = (tot + 63) >> 6;
        int x = tiles;
#pragma unroll
        for (int off = 1; off < 64; off <<= 1) { int y = __shfl_up(x, off, 64); if (c >= off) x += y; }
        int tileBase = x - tiles;
        csPad[l * 64 + c] = tileBase * 64;
        int* cot = cot_all + cTILEOFF[l];
        for (int i = 0; i < tiles; i++) {
            int vv = tot - (i << 6); if (vv > 64) vv = 64;
            cot[tileBase + i] = c | (vv << 8);      // packed descriptor
        }
        int nT = __shfl(x, 63, 64);
        int mt = cMT[l];
        for (int i = nT + c; i < mt; i += 64) cot[i] = -1;
        return;
    }
    // ---- node block-offset scan (original k_nscan2) ----
    int l = blk - 5;
    int o = cNBLKOFF[l];
    int nb = cNBLKOFF[l + 1] - o;
    int v = (t < nb) ? bsum[o + t] : 0;
    int s = v;
#pragma unroll
    for (int off = 1; off < 64; off <<= 1) { int y = __shfl_up(s, off, 64); if (t >= off) s += y; }
    int tot = __shfl(s, 63, 64);
    if (t < nb) boff[o + t] = s - v;
    int t2 = t + 64;
    int v2 = (t2 < nb) ? bsum[o + t2] : 0;
    int s2 = v2;
#pragma unroll
    for (int off = 1; off < 64; off <<= 1) { int y = __shfl_up(s2, off, 64); if (t >= off) s2 += y; }
    if (t2 < nb) boff[o + t2] = tot + s2 - v2;
}

// ---- merged scatter: one edge pass -> cbrec (cell order, carries posd), darec -------
__global__ void k_scatter(P5f PS, P5i EI, const int* __restrict__ bb, const int* __restrict__ csPad,
                          const int* __restrict__ dbase, const int* __restrict__ boff,
                          int* __restrict__ rank,
                          int4* __restrict__ cbrec, int4* __restrict__ darec) {
    int b = blockIdx.x;
    int l = lvl_e(b);
    int lb = b - cEBLKOFF[l];
    int E = cE[l];
    __shared__ int base[64];
    __shared__ int cnt[64];
    int t = threadIdx.x;
    if (t < 64) { base[t] = bb[(size_t)b * 64 + t] + csPad[l * 64 + t]; cnt[t] = 0; }
    __syncthreads();
    int e = lb * 256 + t;
    if (e >= E) return;
    const float* ps = PS.p[l];
    float v0 = ps[e * 3] * 4.f, v1 = ps[e * 3 + 1] * 4.f, v2 = ps[e * 3 + 2] * 4.f;
    float f0 = floorf(v0), f1v = floorf(v1), f2v = floorf(v2);
    int c = (int)f0 * 16 + (int)f1v * 4 + (int)f2v;
    int r = atomicAdd(&cnt[c], 1);
    int posc = base[c] + r;
    const int* ei = EI.p[l];
    int src = ei[e];
    int dst = ei[E + e];
    int posd = dbase[cNOFF[l] + dst] + boff[cNBLKOFF[l] + (dst >> 8)]
             + atomicAdd(&rank[cNOFF[l] + dst], 1);
    unsigned int fxfy = (unsigned int)__half_as_ushort(__float2half(v0 - f0))
                      | ((unsigned int)__half_as_ushort(__float2half(v1 - f1v)) << 16);
    unsigned int fzp  = (unsigned int)__half_as_ushort(__float2half(v2 - f2v));
    int4 rc;
    rc.x = src; rc.y = posd; rc.z = (int)fxfy; rc.w = (int)fzp;   // posd -> dst-order store
    cbrec[cSEOFF[l] + posc] = rc;
    int4 rd;
    rd.x = src | (dst << 16); rd.y = c; rd.z = (int)fxfy; rd.w = (int)fzp;
    darec[cEOFF[l] + posd] = rd;
}

// ---- Fused Conv A (32-node blocks): pipelined staging, all-wave MFMA tail -----------
__launch_bounds__(256)
__global__ void conv_a_fused(P5f X, P5f RootA, P5f BiasA,
                             const int4* __restrict__ darec, const uint4* __restrict__ wasw,
                             const int* __restrict__ dbase, const int* __restrict__ boff,
                             const int* __restrict__ dcnt, ushortT* __restrict__ f1bf) {
    __shared__ float S[32 * 126];          // 16128 B; Sbf (32x136 bf16) overlaid after convert
    __shared__ int infoS[256];
    __shared__ unsigned int fxyS[256];
    __shared__ unsigned int fzS[256];
    __shared__ float xsS[256];
    int b = blockIdx.x;
    int l = (b >= cABLK32[4]) ? 4 : (b >= cABLK32[3]) ? 3 : (b >= cABLK32[2]) ? 2 : (b >= cABLK32[1]) ? 1 : 0;
    int node0 = (b - cABLK32[l]) * 32;
    int n = cN[l];
    int nn = n - node0; if (nn > 32) nn = 32;
    int t = threadIdx.x;
    int lane = t & 63, wv = t >> 6;
    int C1 = l ? 64 : 32;
    int numN = C1 >> 4;                    // 2 (l0) or 4
    int nTask = 2 * numN;                  // 4 or 8: (node-group g, col-group w')
    // hoist level-constant GEMM B-frags into regs at entry (latency hidden by scatter)
    const uint4* wl = wasw + cWAOFF[l];
    uint4 wfrag0[4], wfrag1[4];
    {
        int w0 = wv % numN;                // task wv  -> g = wv / numN
#pragma unroll
        for (int st = 0; st < 4; st++) wfrag0[st] = wl[(st * numN + w0) * 64 + lane];
        if (nTask == 8) {
            int w1 = wv;                   // task wv+4 -> g = 1, w' = wv (numN==4)
#pragma unroll
            for (int st = 0; st < 4; st++) wfrag1[st] = wl[(st * numN + w1) * 64 + lane];
        }
    }
    for (int i = t; i < 32 * 126; i += 256) S[i] = 0.f;
    const int* db = dbase + cNOFF[l];
    const int* bo = boff + cNBLKOFF[l];
    int estart = db[node0] + bo[node0 >> 8];
    int vend = node0 + nn;
    int eend = (vend >= n) ? cE[l] : (db[vend] + bo[vend >> 8]);
    const float* x = X.p[l];
    const int4* dr = darec + cEOFF[l];
    const int bx = t & 1, by = (t >> 1) & 1, bz = (t >> 2) & 1;
    // prefetch chunk 0 into regs
    int4 rcur; float xcur;
    if (estart + t < eend) { rcur = dr[estart + t]; xcur = x[rcur.x & 0xFFFF]; }
    for (int cs = estart; cs < eend; cs += 256) {
        if (cs + t < eend) {
            infoS[t] = ((((unsigned int)rcur.x) >> 16) - node0) * 64 + rcur.y;
            fxyS[t] = (unsigned int)rcur.z;
            fzS[t] = (unsigned int)rcur.w;
            xsS[t] = xcur;
        }
        __syncthreads();
        // issue next chunk's loads NOW (hidden under this chunk's scatter)
        int pn = cs + 256 + t;
        if (pn < eend) { rcur = dr[pn]; xcur = x[rcur.x & 0xFFFF]; }
        int ne = eend - cs; if (ne > 256) ne = 256;
        for (int j = (t >> 3); j < ne; j += 32) {
            int info = infoS[j];
            int nl = info >> 6, cell = info & 63;
            unsigned int uz = fxyS[j];
            float fx = h2f_lo(uz), fy = h2f_hi(uz), fz = h2f_lo(fzS[j]);
            float xs = xsS[j];
            int cx = cell >> 4, cy = (cell >> 2) & 3, cz = cell & 3;
            int slot = (cx + bx) * 25 + (cy + by) * 5 + (cz + bz);
            float wc = (bx ? fx : 1.f - fx) * (by ? fy : 1.f - fy) * (bz ? fz : 1.f - fz);
            atomicAdd(&S[nl * 126 + slot], wc * xs);
        }
        __syncthreads();
    }
    // in-place convert: S (f32, stride 126) -> Sbf (bf16, stride 136) overlaid on S
    ushortT* Sbf = (ushortT*)S;
    float v[17];
#pragma unroll
    for (int j = 0; j < 17; j++) {
        int i = t + 256 * j;               // i < 4352 = 32*136
        int node = i / 136, k = i % 136;
        v[j] = (i < 4352 && k < 126) ? S[node * 126 + k] : 0.f;
    }
    __syncthreads();
#pragma unroll
    for (int j = 0; j < 17; j++) {
        int i = t + 256 * j;
        if (i < 4352) Sbf[i] = f2bf(v[j]);
    }
    __syncthreads();
    // GEMM tail: all 4 waves active at every level
    int q = lane >> 4, m = lane & 15;
    const int* dcl = dcnt + cNOFF[l];
    ushortT* f1bfl = f1bf + cF1OFF[l];
    auto do_task = [&](int task, const uint4* wf) {
        int g = task / numN;               // node group 0/1
        int w = task - g * numN;           // col group
        f32x4 acc = (f32x4){0.f, 0.f, 0.f, 0.f};
#pragma unroll
        for (int st = 0; st < 4; st++) {
            bf16x8 a = *(const bf16x8*)&Sbf[(16 * g + m) * 136 + st * 32 + q * 8];
            bf16x8 bw = __builtin_bit_cast(bf16x8, wf[st]);
            acc = __builtin_amdgcn_mfma_f32_16x16x32_bf16(a, bw, acc, 0, 0, 0);
        }
        int ch = w * 16 + m;
        float rv = RootA.p[l][ch], bv = BiasA.p[l][ch];
#pragma unroll
        for (int rr = 0; rr < 4; rr++) {
            int row = 16 * g + q * 4 + rr;
            if (row < nn) {
                int gnode = node0 + row;
                int dv = dcl[gnode];
                float d = (float)(dv > 1 ? dv : 1);
                float o = acc[rr] / d + x[gnode] * rv + bv;
                f1bfl[(size_t)gnode * C1 + ch] = f2bf(fmaxf(o, 0.f));
            }
        }
    };
    do_task(wv, wfrag0);                   // l0: tasks 0..3; l>0: tasks 0..3 then 4..7
    if (nTask == 8) do_task(wv + 4, wfrag1);
}

// ---- async A-tile stage: global f1bf rows -> LDS, source-side XOR swizzle -----------
// slot(row,chunk) = row*NC + (chunk ^ (row & (NC-1))); LDS dest is linear (m104).
template<int CIN>
__device__ __forceinline__ void stage_issue(const ushortT* __restrict__ f1bfl, int srcx,
                                            ushortT* lregion, int lane) {
    const int NC = CIN / 8;               // 16B chunks per row
#pragma unroll
    for (int i = 0; i < NC; i++) {        // NC issues of 64 lanes x 16B
        int s = i * 64 + lane;
        int row = s / NC;
        int cp = s & (NC - 1);
        int chunk = cp ^ (row & (NC - 1));
        int src = __shfl(srcx, row, 64);
        const ushortT* gp = f1bfl + (size_t)src * CIN + chunk * 8;
        __builtin_amdgcn_global_load_lds(
            (const __attribute__((address_space(1))) void*)gp,
            (__attribute__((address_space(3))) void*)(lregion + (size_t)i * 512),
            16, 0, 0);
    }
}

// ---- read staged A-frags (same XOR) -> registers ------------------------------------
template<int CIN>
__device__ __forceinline__ void read_ahr(const ushortT* st, bf16x8 (&ahr)[4][CIN / 32],
                                         int q, int m) {
    const int NC = CIN / 8;
#pragma unroll
    for (int mt = 0; mt < 4; mt++) {
        int row = 16 * mt + m;
#pragma unroll
        for (int s = 0; s < CIN / 32; s++) {
            int chunk = s * 4 + q;
            int cp = chunk ^ (row & (NC - 1));
            ahr[mt][s] = *(const bf16x8*)&st[(size_t)row * NC * 8 + cp * 8];
        }
    }
}

// ---- Conv B tile compute: MFMA -> LDS tile assembly -> full-line dst-order store ----
template<int CIN>
__device__ __forceinline__ void conv_b_tile_compute(
    const uint4* __restrict__ whiL, __half* __restrict__ pout,
    bf16x8 (&ahr)[4][CIN / 32], const float* __restrict__ wxy,
    const float* __restrict__ fzp, const int* __restrict__ pd, int valid,
    int cell, int lane, int wv, __half* __restrict__ outS) {
    const int T = CIN / 32;
    int q = lane >> 4, m = lane & 15;
    int cx = cell >> 4, cy = (cell >> 2) & 3, cz = cell & 3;
    float fzr[16];
#pragma unroll
    for (int mt = 0; mt < 4; mt++)
#pragma unroll
        for (int rr = 0; rr < 4; rr++)
            fzr[mt * 4 + rr] = fzp[16 * mt + q * 4 + rr];

    uint4 wb[2][2 * T];
    auto loadw = [&](int xy, uint4* dst) {
        int bx = xy & 1, by = xy >> 1;
        int s0 = (cx + bx) * 25 + (cy + by) * 5 + cz;
#pragma unroll
        for (int st = 0; st < T; st++) {
            dst[st]     = whiL[((size_t)(s0 * T + st) * 4 + wv) * 64 + lane];
            dst[T + st] = whiL[((size_t)((s0 + 1) * T + st) * 4 + wv) * 64 + lane];
        }
    };
    loadw(0, wb[0]);

    f32x4 acc[4];
#pragma unroll
    for (int mt = 0; mt < 4; mt++) acc[mt] = (f32x4){0.f, 0.f, 0.f, 0.f};

#pragma unroll
    for (int xy = 0; xy < 4; xy++) {
        uint4* cur = wb[xy & 1];
        if (xy < 3) loadw(xy + 1, wb[(xy + 1) & 1]);
        f32x4 C0[4], C1[4];
#pragma unroll
        for (int mt = 0; mt < 4; mt++) {
            C0[mt] = (f32x4){0.f, 0.f, 0.f, 0.f};
            C1[mt] = (f32x4){0.f, 0.f, 0.f, 0.f};
        }
#pragma unroll
        for (int st = 0; st < T; st++) {
            bf16x8 b0 = __builtin_bit_cast(bf16x8, cur[st]);
            bf16x8 b1 = __builtin_bit_cast(bf16x8, cur[T + st]);
#pragma unroll
            for (int mt = 0; mt < 4; mt++) {
                C0[mt] = __builtin_amdgcn_mfma_f32_16x16x32_bf16(ahr[mt][st], b0, C0[mt], 0, 0, 0);
                C1[mt] = __builtin_amdgcn_mfma_f32_16x16x32_bf16(ahr[mt][st], b1, C1[mt], 0, 0, 0);
            }
        }
        const float* wrow = &wxy[xy * 64];
#pragma unroll
        for (int mt = 0; mt < 4; mt++)
#pragma unroll
            for (int rr = 0; rr < 4; rr++) {
                float wxyv = wrow[16 * mt + q * 4 + rr];   // LDS broadcast (4 addrs/wave)
                float dlt = C1[mt][rr] - C0[mt][rr];
                float tt = fmaf(fzr[mt * 4 + rr], dlt, C0[mt][rr]);
                acc[mt][rr] = fmaf(wxyv, tt, acc[mt][rr]);
            }
    }
    // assemble output tile in LDS (wave writes its 16-col slice)
#pragma unroll
    for (int mt = 0; mt < 4; mt++)
#pragma unroll
        for (int rr = 0; rr < 4; rr++) {
            int row = 16 * mt + q * 4 + rr;
            outS[row * 68 + 16 * wv + m] = __float2half(acc[mt][rr]);
        }
    __syncthreads();
    // cooperative full-line scatter: 8 lanes x 16B = one 128B row at pd[row]
    int t = (wv << 6) | lane;
#pragma unroll
    for (int p = 0; p < 2; p++) {
        int row = p * 32 + (t >> 3);
        int part = t & 7;
        if (row < valid) {
            uint4 vv = *(const uint4*)&outS[row * 68 + part * 8];
            *(uint4*)&pout[(size_t)pd[row] * 64 + part * 8] = vv;
        }
    }
    __syncthreads();   // outS reusable for next tile
}

// ---- conv B pair: tile1's cbrec+A staged async to LDS under tile0's compute ---------
template<int CIN>
__device__ __forceinline__ void conv_b_pair(
    const ushortT* __restrict__ f1bfl, const int4* __restrict__ cbl,
    const uint4* __restrict__ whiL, __half* __restrict__ pout,
    int d0, int d1, int tb0, int tb1, int lane, int wv,
    ushortT* stage0, ushortT* stage1, __half* __restrict__ outS,
    float* __restrict__ wxy0, float* __restrict__ fz0, int* __restrict__ pd0,
    float* __restrict__ wxy1, float* __restrict__ fz1, int* __restrict__ pd1) {
    const int T = CIN / 32;
    int q = lane >> 4, m = lane & 15;
    bool has1 = d1 >= 0;
    int cell0 = d0 & 63, v0 = d0 >> 8;
    int cell1 = has1 ? (d1 & 63) : 0, v1 = has1 ? (d1 >> 8) : 0;

    int4 r0, r1;
    if (lane < v0) r0 = cbl[tb0 + lane]; else { r0.x = 0; r0.y = 0; r0.z = 0; r0.w = 0; }
    if (lane < v1) r1 = cbl[tb1 + lane]; else { r1.x = 0; r1.y = 0; r1.z = 0; r1.w = 0; }

    {
        unsigned int uz = (unsigned int)r0.z;
        float fx = h2f_lo(uz), fy = h2f_hi(uz);
        float gx = 1.f - fx, gy = 1.f - fy;
        wxy0[0 * 64 + lane] = gx * gy;
        wxy0[1 * 64 + lane] = fx * gy;
        wxy0[2 * 64 + lane] = gx * fy;
        wxy0[3 * 64 + lane] = fx * fy;
        fz0[lane] = h2f_lo((unsigned int)r0.w);
        pd0[lane] = r0.y;
    }
    {
        unsigned int uz = (unsigned int)r1.z;
        float fx = h2f_lo(uz), fy = h2f_hi(uz);
        float gx = 1.f - fx, gy = 1.f - fy;
        wxy1[0 * 64 + lane] = gx * gy;
        wxy1[1 * 64 + lane] = fx * gy;
        wxy1[2 * 64 + lane] = gx * fy;
        wxy1[3 * 64 + lane] = fx * fy;
        fz1[lane] = h2f_lo((unsigned int)r1.w);
        pd1[lane] = r1.y;
    }
    __builtin_amdgcn_wave_barrier();   // pin LDS write->read order (same-wave DS in-order)

    // issue both A stages (async, zero VGPR); waves duplicate same-value writes (benign)
    stage_issue<CIN>(f1bfl, r0.x, stage0, lane);
    if (has1) stage_issue<CIN>(f1bfl, r1.x, stage1, lane);

    // wait only for stage0 (tile1's NC loads stay in flight across tile0's compute)
    if (has1) {
        if (CIN == 64) asm volatile("s_waitcnt vmcnt(8)" ::: "memory");
        else           asm volatile("s_waitcnt vmcnt(4)" ::: "memory");
    } else {
        asm volatile("s_waitcnt vmcnt(0)" ::: "memory");
    }

    bf16x8 ahr[4][T];
    read_ahr<CIN>(stage0, ahr, q, m);
    conv_b_tile_compute<CIN>(whiL, pout, ahr, wxy0, fz0, pd0, v0, cell0, lane, wv, outS);

    if (has1) {
        asm volatile("s_waitcnt vmcnt(0)" ::: "memory");
        read_ahr<CIN>(stage1, ahr, q, m);
        conv_b_tile_compute<CIN>(whiL, pout, ahr, wxy1, fz1, pd1, v1, cell1, lane, wv, outS);
    }
}

// ---- merged: rgemm (b<609) | conv B tile pairs — independent outputs f2 / Ph --------
__launch_bounds__(256, 3)
__global__ void conv_brg(const ushortT* __restrict__ f1bf, const int4* __restrict__ cbrec,
                         const uint4* __restrict__ whi, const int* __restrict__ cot,
                         __half* __restrict__ Ph,
                         const uint4* __restrict__ rb, float* __restrict__ f2) {
    __shared__ __align__(16) ushortT stageS[2][4096];  // 2 tiles x 8KB (worst CIN=64)
    __shared__ __align__(16) __half outS[64 * 68];     // 8704B output assembly tile
    __shared__ float wxyS[2][256];
    __shared__ float fzS[2][64];
    __shared__ int pdS[2][64];
    int t = threadIdx.x;
    int wv = t >> 6, lane = t & 63;
    int blk = blockIdx.x;
    if (blk < 609) {
        // ---- R-gemm: f2 = f1bf @ rootb (independent of conv_b; overlaps it) ----
        int b = blk;
        int l = (b >= cRGB[4]) ? 4 : (b >= cRGB[3]) ? 3 : (b >= cRGB[2]) ? 2 : (b >= cRGB[1]) ? 1 : 0;
        int node0 = (b - cRGB[l]) * 64;
        int n = cN[l];
        int nn = n - node0; if (nn > 64) nn = 64;
        int q = lane >> 4, m = lane & 15;
        const int CIN = l ? 64 : 32;
        const int T = l ? 2 : 1;
        const ushortT* fl = f1bf + cF1OFF[l];
        const uint4* rbl = rb + cRBOFF[l];
        f32x4 C[4];
#pragma unroll
        for (int mt = 0; mt < 4; mt++) C[mt] = (f32x4){0.f, 0.f, 0.f, 0.f};
        for (int st = 0; st < T; st++) {
            bf16x8 bh = __builtin_bit_cast(bf16x8, rbl[(st * 4 + wv) * 64 + lane]);
#pragma unroll
            for (int mt = 0; mt < 4; mt++) {
                int row = 16 * mt + m;
                int nr = node0 + row; if (nr > n - 1) nr = n - 1;
                bf16x8 a = *(const bf16x8*)&fl[(size_t)nr * CIN + st * 32 + q * 8];
                C[mt] = __builtin_amdgcn_mfma_f32_16x16x32_bf16(a, bh, C[mt], 0, 0, 0);
            }
        }
#pragma unroll
        for (int mt = 0; mt < 4; mt++)
#pragma unroll
            for (int rr = 0; rr < 4; rr++) {
                int row = 16 * mt + q * 4 + rr;
                if (row < nn)
                    f2[(size_t)(cNOFF[l] + node0 + row) * 64 + 16 * wv + m] = C[mt][rr];
            }
        return;
    }
    // ---- conv B pair path ----
    int b = blk - 609;
    int l = (b >= cPAIR[4]) ? 4 : (b >= cPAIR[3]) ? 3 : (b >= cPAIR[2]) ? 2 : (b >= cPAIR[1]) ? 1 : 0;
    int p = b - cPAIR[l];
    int t0 = 2 * p, t1 = t0 + 1;
    const int* cotl = cot + cTILEOFF[l];
    int d0 = cotl[t0];
    int d1 = (t1 < cMT[l]) ? cotl[t1] : -1;
    if (d0 < 0) return;                    // block-uniform
    int tb0 = t0 * 64, tb1 = t1 * 64;
    if (l == 0)
        conv_b_pair<32>(f1bf, cbrec, whi, Ph, d0, d1, tb0, tb1, lane, wv,
                        stageS[0], stageS[1], outS,
                        wxyS[0], fzS[0], pdS[0], wxyS[1], fzS[1], pdS[1]);
    else
        conv_b_pair<64>(f1bf + cF1OFF[l], cbrec + cSEOFF[l], whi + cWOFF[l],
                        Ph + (size_t)cEOFF[l] * 64, d0, d1, tb0, tb1, lane, wv,
                        stageS[0], stageS[1], outS,
                        wxyS[0], fzS[0], pdS[0], wxyS[1], fzS[1], pdS[1]);
}

// ---- fused node epilogue + readout: 8-node windows, 2-deep vectorized Ph stream -----
// uint2/lane = 8B: one wave-load covers 4 rows x 64ch; main loop issues TWO independent
// loads (8 rows) per iteration for MLP. Lane L accumulates channels 4*(L&15)..+3 for
// row-parity L>>4; node-end merge = shfl_xor(16)+shfl_xor(32). Run-boundary atomics
// only (R9 lesson); lanes<16 issue 4 consecutive-addr adds.
__launch_bounds__(256)
__global__ void node_read(const __half* __restrict__ Ph,
                          const int* __restrict__ dbase, const int* __restrict__ boff,
                          const int* __restrict__ dcnt, P5f BiasB, P5i Batch,
                          const float* __restrict__ f2,
                          float* __restrict__ hsum, float* __restrict__ gcnt) {
    const int RC[6] = {0, 2500, 3750, 4375, 4688, 4845};   // ceil(N/8) prefix
    int t = threadIdx.x;
    int lane = t & 63;
    int w = blockIdx.x * 4 + (t >> 6);
    if (w >= 4845) return;
    int l = (w >= RC[4]) ? 4 : (w >= RC[3]) ? 3 : (w >= RC[2]) ? 2 : (w >= RC[1]) ? 1 : 0;
    int base = (w - RC[l]) * 8;
    int Nl = cN[l];
    int nn = Nl - base; if (nn > 8) nn = 8;
    const __half* PhL = Ph + (size_t)cEOFF[l] * 64;
    const float* f2b = f2 + (size_t)(cNOFF[l] + base) * 64;
    int c4 = (lane & 15) * 4;              // this lane's channel quad
    int rp = lane >> 4;                    // row parity 0..3
    float4 bias4 = *(const float4*)&BiasB.p[l][c4];
    // lane-parallel metadata load for the window's 8 nodes, broadcast via shfl
    int myStart = 0, myDeg = 0, myG = 0;
    if (lane < nn) {
        int node = base + lane;
        myStart = dbase[cNOFF[l] + node] + boff[cNBLKOFF[l] + (node >> 8)];
        myDeg = dcnt[cNOFF[l] + node];
        myG = Batch.p[l][node];
    }
    int curg = -1;
    float h0 = 0.f, h1 = 0.f, h2 = 0.f, h3 = 0.f;   // run accumulator (channel quad)
    int crun = 0;
    for (int j = 0; j < nn; j++) {
        int start = __shfl(myStart, j, 64);
        int deg = __shfl(myDeg, j, 64);
        int g = __shfl(myG, j, 64);
        float a0 = 0.f, a1 = 0.f, a2 = 0.f, a3 = 0.f;
        float b0 = 0.f, b1 = 0.f, b2 = 0.f, b3 = 0.f;
        int k = 0;
        for (; k + 8 <= deg; k += 8) {      // two independent 512B wave-loads in flight
            uint2 v = *(const uint2*)(PhL + (size_t)(start + k) * 64 + lane * 4);
            uint2 u = *(const uint2*)(PhL + (size_t)(start + k + 4) * 64 + lane * 4);
            a0 += h2f_lo(v.x); a1 += h2f_hi(v.x);
            a2 += h2f_lo(v.y); a3 += h2f_hi(v.y);
            b0 += h2f_lo(u.x); b1 += h2f_hi(u.x);
            b2 += h2f_lo(u.y); b3 += h2f_hi(u.y);
        }
        for (; k + 4 <= deg; k += 4) {      // 4 rows = 512B per wave-load
            uint2 v = *(const uint2*)(PhL + (size_t)(start + k) * 64 + lane * 4);
            a0 += h2f_lo(v.x); a1 += h2f_hi(v.x);
            a2 += h2f_lo(v.y); a3 += h2f_hi(v.y);
        }
        if (k < deg && k + rp < deg) {      // tail rows, same lane->channel mapping
            uint2 v = *(const uint2*)(PhL + (size_t)(start + k) * 64 + lane * 4);
            a0 += h2f_lo(v.x); a1 += h2f_hi(v.x);
            a2 += h2f_lo(v.y); a3 += h2f_hi(v.y);
        }
        a0 += b0; a1 += b1; a2 += b2; a3 += b3;
        // merge the 4 row-parities: lanes L, L^16, L^32, L^48 share a channel quad
        a0 += __shfl_xor(a0, 16, 64); a1 += __shfl_xor(a1, 16, 64);
        a2 += __shfl_xor(a2, 16, 64); a3 += __shfl_xor(a3, 16, 64);
        a0 += __shfl_xor(a0, 32, 64); a1 += __shfl_xor(a1, 32, 64);
        a2 += __shfl_xor(a2, 32, 64); a3 += __shfl_xor(a3, 32, 64);
        float dinv = 1.f / (float)(deg > 1 ? deg : 1);
        float4 fr = *(const float4*)&f2b[(size_t)j * 64 + c4];
        float s0 = fmaxf(a0 * dinv + fr.x + bias4.x, 0.f);
        float s1 = fmaxf(a1 * dinv + fr.y + bias4.y, 0.f);
        float s2 = fmaxf(a2 * dinv + fr.z + bias4.z, 0.f);
        float s3 = fmaxf(a3 * dinv + fr.w + bias4.w, 0.f);
        if (g != curg) {
            if (curg >= 0) {
                if (lane < 16) {
                    float* hp = &hsum[curg * 320 + l * 64 + c4];
                    atomicAdd(hp + 0, h0); atomicAdd(hp + 1, h1);
                    atomicAdd(hp + 2, h2); atomicAdd(hp + 3, h3);
                }
                if (lane == 0) atomicAdd(&gcnt[l * 64 + curg], (float)crun);
            }
            curg = g; h0 = h1 = h2 = h3 = 0.f; crun = 0;
        }
        h0 += s0; h1 += s1; h2 += s2; h3 += s3;
        crun++;
    }
    if (curg >= 0) {
        if (lane < 16) {
            float* hp = &hsum[curg * 320 + l * 64 + c4];
            atomicAdd(hp + 0, h0); atomicAdd(hp + 1, h1);
            atomicAdd(hp + 2, h2); atomicAdd(hp + 3, h3);
        }
        if (lane == 0) atomicAdd(&gcnt[l * 64 + curg], (float)crun);
    }
}

// ---------------- FC + log_softmax: one block per graph ----------------
__global__ void fc_kernel(const float* __restrict__ hsum, const float* __restrict__ gcnt,
                          const float* __restrict__ fcw, const float* __restrict__ fcb,
                          float* __restrict__ out) {
    int g = blockIdx.x;
    int lane = threadIdx.x;  // 64
    float partial[10];
#pragma unroll
    for (int t = 0; t < 10; t++) partial[t] = 0.f;
#pragma unroll
    for (int k = 0; k < 5; k++) {
        int j = k * 64 + lane;
        float c = fmaxf(gcnt[k * 64 + g], 1.f);
        float h = hsum[g * 320 + j] / c;
        const float* fw = fcw + j * 10;
#pragma unroll
        for (int t = 0; t < 10; t++) partial[t] = fmaf(h, fw[t], partial[t]);
    }
#pragma unroll
    for (int off = 32; off >= 1; off >>= 1)
#pragma unroll
        for (int t = 0; t < 10; t++) partial[t] += __shfl_xor(partial[t], off, 64);
    if (lane == 0) {
        float logit[10];
#pragma unroll
        for (int t = 0; t < 10; t++) logit[t] = partial[t] + fcb[t];
        float m = logit[0];
#pragma unroll
        for (int t = 1; t < 10; t++) m = fmaxf(m, logit[t]);
        float sum = 0.f;
#pragma unroll
        for (int t = 0; t < 10; t++) sum += expf(logit[t] - m);
        float lse = m + logf(sum);
#pragma unroll
        for (int t = 0; t < 10; t++) out[g * 10 + t] = logit[t] - lse;
    }
}

extern "C" void kernel_launch(void* const* d_in, const int* in_sizes, int n_in,
                              void* d_out, int out_size, void* d_ws, size_t ws_size,
                              hipStream_t stream) {
    int* wsI = (int*)d_ws;
    int*   dcnt  = wsI;                          // 38750
    int*   rank  = dcnt + 38750;                 // 38750
    float* hsum  = (float*)(rank + 38750);       // 20480  (hsum[g*320 + l*64 + lane])
    float* gcnt  = hsum + 20480;                 // 320
    float* f2    = gcnt + 320;                   // 2,480,000 (R from rgemm; read-only in node_read)
    int*   dbase = (int*)(f2 + 2480000);         // 38750
    int*   bsum  = dbase + 38750;                // 160
    int*   boff  = bsum + 160;                   // 160
    int*   cpos  = boff + 160;                   // 620000 (unused after dst-order Ph)
    int*   bb    = cpos + 620000;                // 155136
    int*   csPad = bb + 155136;                  // 320
    int*   cellTot = csPad + 320;                // 320
    int*   cot   = cellTot + 320;                // 10008
    int4*  cbrec = (int4*)(((size_t)(cot + 10008) + 15) & ~(size_t)15);   // 640512 recs
    int4*  darec = cbrec + 640512;               // 620000 recs
    ushortT* f1bf = (ushortT*)(darec + 620000);  // 1,840,000 ushorts
    uint4* whi   = (uint4*)(((size_t)(f1bf + 1840000) + 15) & ~(size_t)15);  // 288000
    uint4* rbsw  = whi + 288000;                 // 2304
    uint4* wasw  = rbsw + 2304;                  // 4608
    __half* Ph   = (__half*)(wasw + 4608);       // 620000 rows of 64 (dst-ordered per level)

    hipMemsetAsync(dcnt, 0, (size_t)(38750 * 2 + 20480 + 320) * sizeof(int), stream);

    P5f PS, X, WA, RootA, BiasA, WB, RootB, BiasB;
    P5i EI, Batch;
    for (int l = 0; l < 5; l++) {
        const int b = l * 10;
        X.p[l]     = (const float*)d_in[b + 0];
        PS.p[l]    = (const float*)d_in[b + 1];
        EI.p[l]    = (const int*)d_in[b + 2];
        Batch.p[l] = (const int*)d_in[b + 3];
        WA.p[l]    = (const float*)d_in[b + 4];
        RootA.p[l] = (const float*)d_in[b + 5];
        BiasA.p[l] = (const float*)d_in[b + 6];
        WB.p[l]    = (const float*)d_in[b + 7];
        RootB.p[l] = (const float*)d_in[b + 8];
        BiasB.p[l] = (const float*)d_in[b + 9];
    }

    // prep: hist + weight-swizzle fused (wswz independent, hides under hist)
    k_hist_wswz<<<3576, 256, 0, stream>>>(PS, EI, dcnt, bb, WB, RootB, WA,
                                          whi, rbsw, wasw);
    k_scan1<<<234, 256, 0, stream>>>(bb, cellTot, dcnt, dbase, bsum);
    k_scan2<<<10, 64, 0, stream>>>(cellTot, csPad, cot, bsum, boff);
    k_scatter<<<2424, 256, 0, stream>>>(PS, EI, bb, csPad, dbase, boff, rank,
                                        cbrec, darec);

    // conv A (all levels, 32-node blocks, pipelined staging) -> f1bf
    conv_a_fused<<<1214, 256, 0, stream>>>(X, RootA, BiasA, darec, wasw,
                                           dbase, boff, dcnt, f1bf);

    // rgemm + conv B fused (independent outputs f2 / Ph; rgemm hides under conv_b)
    conv_brg<<<5614, 256, 0, stream>>>(f1bf, cbrec, whi, cot, Ph, rbsw, f2);

    // fused node epilogue + readout: 2-deep vectorized Ph stream -> run atomics
    node_read<<<1212, 256, 0, stream>>>(Ph, dbase, boff, dcnt, BiasB, Batch, f2,
                                        hsum, gcnt);

    // FC + log_softmax
    fc_kernel<<<64, 64, 0, stream>>>(hsum, gcnt, (const float*)d_in[50], (const float*)d_in[51],
                                     (float*)d_out);
}

// Round 13
// 375.575 us; speedup vs baseline: 1.0306x; 1.0059x over previous
//
#include <hip/hip_runtime.h>
#include <hip/hip_fp16.h>
#include <math.h>

#define NUM_GRAPHS 64

typedef unsigned short ushortT;
typedef __attribute__((ext_vector_type(8))) short bf16x8;
typedef __attribute__((ext_vector_type(4))) float f32x4;

// ---- static level tables ----
constexpr int cN[5]       = {20000, 10000, 5000, 2500, 1250};
constexpr int cE[5]       = {320000, 160000, 80000, 40000, 20000};
constexpr int cNOFF[6]    = {0, 20000, 30000, 35000, 37500, 38750};
constexpr int cEOFF[6]    = {0, 320000, 480000, 560000, 600000, 620000};
constexpr int cEBLKOFF[6] = {0, 1250, 1875, 2188, 2345, 2424};
constexpr int cNBLKOFF[6] = {0, 79, 119, 139, 149, 154};
constexpr int cMT[5]      = {5064, 2564, 1314, 689, 377};
constexpr int cTILEOFF[6] = {0, 5064, 7628, 8942, 9631, 10008};
constexpr int cSEOFF[6]   = {0, 324096, 488192, 572288, 616384, 640512};
constexpr int cF1OFF[6]   = {0, 640000, 1280000, 1600000, 1760000, 1840000};
constexpr int cWOFF[6]    = {0, 32000, 96000, 160000, 224000, 288000};
constexpr int cABLK32[6]  = {0, 625, 938, 1095, 1174, 1214};     // ceil(N/32) prefix
constexpr int cRBOFF[5]   = {0, 256, 768, 1280, 1792};           // rootb swizzle uint4 offsets
constexpr int cWAOFF[6]   = {0, 512, 1536, 2560, 3584, 4608};    // Wa swizzle uint4 offsets
constexpr int cRGB[6]     = {0, 313, 470, 549, 589, 609};        // ceil(N/64) prefix
constexpr int cPAIR[6]    = {0, 2532, 3814, 4471, 4816, 5005};   // ceil(cMT/2) prefix

struct P5f { const float* p[5]; };
struct P5i { const int* p[5]; };

__device__ __forceinline__ int lvl_e(int b) {
    return (b >= cEBLKOFF[4]) ? 4 : (b >= cEBLKOFF[3]) ? 3 : (b >= cEBLKOFF[2]) ? 2 : (b >= cEBLKOFF[1]) ? 1 : 0;
}
__device__ __forceinline__ int lvl_n(int b) {
    return (b >= cNBLKOFF[4]) ? 4 : (b >= cNBLKOFF[3]) ? 3 : (b >= cNBLKOFF[2]) ? 2 : (b >= cNBLKOFF[1]) ? 1 : 0;
}

__device__ __forceinline__ ushortT f2bf(float f) {
    union { float f; unsigned int u; } v; v.f = f;
    unsigned int r = (v.u + 0x7FFFu + ((v.u >> 16) & 1u)) >> 16;
    return (ushortT)r;
}
__device__ __forceinline__ float h2f_lo(unsigned int u) {
    return __half2float(__ushort_as_half((ushortT)(u & 0xFFFFu)));
}
__device__ __forceinline__ float h2f_hi(unsigned int u) {
    return __half2float(__ushort_as_half((ushortT)(u >> 16)));
}

// ---- merged: per-block cell histogram + degree count (b<2424) | weight swizzle ------
__global__ void k_hist_wswz(P5f PS, P5i EI, int* __restrict__ dcnt, int* __restrict__ bb,
                            P5f WB, P5f RootB, P5f WA,
                            uint4* __restrict__ hi4, uint4* __restrict__ rb,
                            uint4* __restrict__ wa) {
    int blk = blockIdx.x;
    int t = threadIdx.x;
    if (blk < 2424) {
        int b = blk;
        int l = lvl_e(b);
        int lb = b - cEBLKOFF[l];
        int E = cE[l];
        __shared__ int h[64];
        if (t < 64) h[t] = 0;
        __syncthreads();
        int e = lb * 256 + t;
        if (e < E) {
            atomicAdd(&dcnt[cNOFF[l] + EI.p[l][E + e]], 1);
            const float* ps = PS.p[l];
            int c = (int)floorf(ps[e * 3] * 4.f) * 16 + (int)floorf(ps[e * 3 + 1] * 4.f) * 4
                  + (int)floorf(ps[e * 3 + 2] * 4.f);
            atomicAdd(&h[c], 1);
        }
        __syncthreads();
        if (t < 64) bb[(size_t)b * 64 + t] = h[t];
        return;
    }
    // ---- weight swizzle path (independent of all prep) ----
    int idx = (blk - 2424) * 256 + t;
    if (idx >= 294912) return;
    if (idx < 288000) {
        int l = (idx >= 224000) ? 4 : (idx >= 160000) ? 3 : (idx >= 96000) ? 2 : (idx >= 32000) ? 1 : 0;
        int local = idx - cWOFF[l];
        int T = l ? 2 : 1, C = l ? 64 : 32;
        int lane = local & 63;
        int blk2 = (local >> 6) & 3;
        int rest = local >> 8;
        int st = rest % T, s = rest / T;
        int q = lane >> 4, n = blk2 * 16 + (lane & 15);
        const float* W = WB.p[l];
        union { ushortT u[8]; uint4 v; } ph;
#pragma unroll
        for (int j = 0; j < 8; j++) {
            int k = st * 32 + q * 8 + j;
            ph.u[j] = f2bf(W[((size_t)s * C + k) * 64 + n]);
        }
        hi4[idx] = ph.v;
    } else if (idx < 290304) {
        int id2 = idx - 288000;
        int l = (id2 >= 1792) ? 4 : (id2 >= 1280) ? 3 : (id2 >= 768) ? 2 : (id2 >= 256) ? 1 : 0;
        int local = id2 - cRBOFF[l];
        int lane = local & 63;
        int w = (local >> 6) & 3;
        int st = local >> 8;
        int q = lane >> 4, n = w * 16 + (lane & 15);
        const float* R = RootB.p[l];
        union { ushortT u[8]; uint4 v; } ph;
#pragma unroll
        for (int j = 0; j < 8; j++) {
            int k = st * 32 + q * 8 + j;
            ph.u[j] = f2bf(R[k * 64 + n]);
        }
        rb[id2] = ph.v;
    } else {
        int id3 = idx - 290304;
        int l = (id3 >= cWAOFF[4]) ? 4 : (id3 >= cWAOFF[3]) ? 3 : (id3 >= cWAOFF[2]) ? 2 : (id3 >= cWAOFF[1]) ? 1 : 0;
        int local = id3 - cWAOFF[l];
        int C1 = l ? 64 : 32;
        int numN = C1 / 16;
        int lane = local & 63;
        int rest = local >> 6;       // st*numN + nb
        int nb = rest % numN, st = rest / numN;
        int q = lane >> 4, n = nb * 16 + (lane & 15);
        const float* Wsrc = WA.p[l];
        union { ushortT u[8]; uint4 v; } ph;
#pragma unroll
        for (int j = 0; j < 8; j++) {
            int k = st * 32 + q * 8 + j;
            ph.u[j] = (k < 125) ? f2bf(Wsrc[k * C1 + n]) : (ushortT)0;
        }
        wa[id3] = ph.v;
    }
}

// ---- merged scan phase 1: cell scan (b<80, wave per (l,c)) | node-degree scan -------
__global__ void k_scan1(int* __restrict__ bb_all, int* __restrict__ cellTot,
                        const int* __restrict__ dcnt, int* __restrict__ dbase,
                        int* __restrict__ bsum) {
    int blk = blockIdx.x;
    int t = threadIdx.x;
    if (blk < 80) {
        int W = blk * 4 + (t >> 6);   // 0..319
        int lane = t & 63;
        int l = W >> 6, c = W & 63;
        int* bb = bb_all + (size_t)cEBLKOFF[l] * 64;
        int nblk = cEBLKOFF[l + 1] - cEBLKOFF[l];
        int run = 0;
        for (int b0 = 0; b0 < nblk; b0 += 64) {
            int b = b0 + lane;
            int v = (b < nblk) ? bb[b * 64 + c] : 0;
            int s = v;
#pragma unroll
            for (int off = 1; off < 64; off <<= 1) { int y = __shfl_up(s, off, 64); if (lane >= off) s += y; }
            if (b < nblk) bb[b * 64 + c] = run + s - v;
            run += __shfl(s, 63, 64);
        }
        if (lane == 0) cellTot[l * 64 + c] = run;
        return;
    }
    // ---- node-degree block scan (original k_nscan1) ----
    int b = blk - 80;
    int l = lvl_n(b);
    int lb = b - cNBLKOFF[l];
    int n = cN[l];
    __shared__ int sh[256];
    int i = lb * 256 + t;
    int v = (i < n) ? dcnt[cNOFF[l] + i] : 0;
    sh[t] = v;
    __syncthreads();
    for (int off = 1; off < 256; off <<= 1) {
        int y = (t >= off) ? sh[t - off] : 0;
        __syncthreads();
        sh[t] += y;
        __syncthreads();
    }
    if (i < n) dbase[cNOFF[l] + i] = sh[t] - v;
    if (t == 255) bsum[b] = sh[255];
}

// ---- merged scan phase 2: tile descriptors (b<5) | node block-offset scan -----------
__global__ void k_scan2(const int* __restrict__ cellTot, int* __restrict__ csPad,
                        int* __restrict__ cot_all,
                        const int* __restrict__ bsum, int* __restrict__ boff) {
    int blk = blockIdx.x;
    int t = threadIdx.x;
    if (blk < 5) {
        int l = blk;
        int c = t;
        int tot = cellTot[l * 64 + c];
        int tiles = (tot + 63) >> 6;
        int x = tiles;
#pragma unroll
        for (int off = 1; off < 64; off <<= 1) { int y = __shfl_up(x, off, 64); if (c >= off) x += y; }
        int tileBase = x - tiles;
        csPad[l * 64 + c] = tileBase * 64;
        int* cot = cot_all + cTILEOFF[l];
        for (int i = 0; i < tiles; i++) {
            int vv = tot - (i << 6); if (vv > 64) vv = 64;
            cot[tileBase + i] = c | (vv << 8);      // packed descriptor
        }
        int nT = __shfl(x, 63, 64);
        int mt = cMT[l];
        for (int i = nT + c; i < mt; i += 64) cot[i] = -1;
        return;
    }
    // ---- node block-offset scan (original k_nscan2) ----
    int l = blk - 5;
    int o = cNBLKOFF[l];
    int nb = cNBLKOFF[l + 1] - o;
    int v = (t < nb) ? bsum[o + t] : 0;
    int s = v;
#pragma unroll
    for (int off = 1; off < 64; off <<= 1) { int y = __shfl_up(s, off, 64); if (t >= off) s += y; }
    int tot = __shfl(s, 63, 64);
    if (t < nb) boff[o + t] = s - v;
    int t2 = t + 64;
    int v2 = (t2 < nb) ? bsum[o + t2] : 0;
    int s2 = v2;
#pragma unroll
    for (int off = 1; off < 64; off <<= 1) { int y = __shfl_up(s2, off, 64); if (t >= off) s2 += y; }
    if (t2 < nb) boff[o + t2] = tot + s2 - v2;
}

// ---- merged scatter: one edge pass -> cbrec (cell order, carries posd), darec -------
__global__ void k_scatter(P5f PS, P5i EI, const int* __restrict__ bb, const int* __restrict__ csPad,
                          const int* __restrict__ dbase, const int* __restrict__ boff,
                          int* __restrict__ rank,
                          int4* __restrict__ cbrec, int4* __restrict__ darec) {
    int b = blockIdx.x;
    int l = lvl_e(b);
    int lb = b - cEBLKOFF[l];
    int E = cE[l];
    __shared__ int base[64];
    __shared__ int cnt[64];
    int t = threadIdx.x;
    if (t < 64) { base[t] = bb[(size_t)b * 64 + t] + csPad[l * 64 + t]; cnt[t] = 0; }
    __syncthreads();
    int e = lb * 256 + t;
    if (e >= E) return;
    const float* ps = PS.p[l];
    float v0 = ps[e * 3] * 4.f, v1 = ps[e * 3 + 1] * 4.f, v2 = ps[e * 3 + 2] * 4.f;
    float f0 = floorf(v0), f1v = floorf(v1), f2v = floorf(v2);
    int c = (int)f0 * 16 + (int)f1v * 4 + (int)f2v;
    int r = atomicAdd(&cnt[c], 1);
    int posc = base[c] + r;
    const int* ei = EI.p[l];
    int src = ei[e];
    int dst = ei[E + e];
    int posd = dbase[cNOFF[l] + dst] + boff[cNBLKOFF[l] + (dst >> 8)]
             + atomicAdd(&rank[cNOFF[l] + dst], 1);
    unsigned int fxfy = (unsigned int)__half_as_ushort(__float2half(v0 - f0))
                      | ((unsigned int)__half_as_ushort(__float2half(v1 - f1v)) << 16);
    unsigned int fzp  = (unsigned int)__half_as_ushort(__float2half(v2 - f2v));
    int4 rc;
    rc.x = src; rc.y = posd; rc.z = (int)fxfy; rc.w = (int)fzp;   // posd -> dst-order store
    cbrec[cSEOFF[l] + posc] = rc;
    int4 rd;
    rd.x = src | (dst << 16); rd.y = c; rd.z = (int)fxfy; rd.w = (int)fzp;
    darec[cEOFF[l] + posd] = rd;
}

// ---- Fused Conv A (32-node blocks): pipelined staging, all-wave MFMA tail -----------
__launch_bounds__(256)
__global__ void conv_a_fused(P5f X, P5f RootA, P5f BiasA,
                             const int4* __restrict__ darec, const uint4* __restrict__ wasw,
                             const int* __restrict__ dbase, const int* __restrict__ boff,
                             const int* __restrict__ dcnt, ushortT* __restrict__ f1bf) {
    __shared__ float S[32 * 126];          // 16128 B; Sbf (32x136 bf16) overlaid after convert
    __shared__ int infoS[256];
    __shared__ unsigned int fxyS[256];
    __shared__ unsigned int fzS[256];
    __shared__ float xsS[256];
    int b = blockIdx.x;
    int l = (b >= cABLK32[4]) ? 4 : (b >= cABLK32[3]) ? 3 : (b >= cABLK32[2]) ? 2 : (b >= cABLK32[1]) ? 1 : 0;
    int node0 = (b - cABLK32[l]) * 32;
    int n = cN[l];
    int nn = n - node0; if (nn > 32) nn = 32;
    int t = threadIdx.x;
    int lane = t & 63, wv = t >> 6;
    int C1 = l ? 64 : 32;
    int numN = C1 >> 4;                    // 2 (l0) or 4
    int nTask = 2 * numN;                  // 4 or 8: (node-group g, col-group w')
    // hoist level-constant GEMM B-frags into regs at entry (latency hidden by scatter)
    const uint4* wl = wasw + cWAOFF[l];
    uint4 wfrag0[4], wfrag1[4];
    {
        int w0 = wv % numN;                // task wv  -> g = wv / numN
#pragma unroll
        for (int st = 0; st < 4; st++) wfrag0[st] = wl[(st * numN + w0) * 64 + lane];
        if (nTask == 8) {
            int w1 = wv;                   // task wv+4 -> g = 1, w' = wv (numN==4)
#pragma unroll
            for (int st = 0; st < 4; st++) wfrag1[st] = wl[(st * numN + w1) * 64 + lane];
        }
    }
    for (int i = t; i < 32 * 126; i += 256) S[i] = 0.f;
    const int* db = dbase + cNOFF[l];
    const int* bo = boff + cNBLKOFF[l];
    int estart = db[node0] + bo[node0 >> 8];
    int vend = node0 + nn;
    int eend = (vend >= n) ? cE[l] : (db[vend] + bo[vend >> 8]);
    const float* x = X.p[l];
    const int4* dr = darec + cEOFF[l];
    const int bx = t & 1, by = (t >> 1) & 1, bz = (t >> 2) & 1;
    // prefetch chunk 0 into regs
    int4 rcur; float xcur;
    if (estart + t < eend) { rcur = dr[estart + t]; xcur = x[rcur.x & 0xFFFF]; }
    for (int cs = estart; cs < eend; cs += 256) {
        if (cs + t < eend) {
            infoS[t] = ((((unsigned int)rcur.x) >> 16) - node0) * 64 + rcur.y;
            fxyS[t] = (unsigned int)rcur.z;
            fzS[t] = (unsigned int)rcur.w;
            xsS[t] = xcur;
        }
        __syncthreads();
        // issue next chunk's loads NOW (hidden under this chunk's scatter)
        int pn = cs + 256 + t;
        if (pn < eend) { rcur = dr[pn]; xcur = x[rcur.x & 0xFFFF]; }
        int ne = eend - cs; if (ne > 256) ne = 256;
        for (int j = (t >> 3); j < ne; j += 32) {
            int info = infoS[j];
            int nl = info >> 6, cell = info & 63;
            unsigned int uz = fxyS[j];
            float fx = h2f_lo(uz), fy = h2f_hi(uz), fz = h2f_lo(fzS[j]);
            float xs = xsS[j];
            int cx = cell >> 4, cy = (cell >> 2) & 3, cz = cell & 3;
            int slot = (cx + bx) * 25 + (cy + by) * 5 + (cz + bz);
            float wc = (bx ? fx : 1.f - fx) * (by ? fy : 1.f - fy) * (bz ? fz : 1.f - fz);
            atomicAdd(&S[nl * 126 + slot], wc * xs);
        }
        __syncthreads();
    }
    // in-place convert: S (f32, stride 126) -> Sbf (bf16, stride 136) overlaid on S
    ushortT* Sbf = (ushortT*)S;
    float v[17];
#pragma unroll
    for (int j = 0; j < 17; j++) {
        int i = t + 256 * j;               // i < 4352 = 32*136
        int node = i / 136, k = i % 136;
        v[j] = (i < 4352 && k < 126) ? S[node * 126 + k] : 0.f;
    }
    __syncthreads();
#pragma unroll
    for (int j = 0; j < 17; j++) {
        int i = t + 256 * j;
        if (i < 4352) Sbf[i] = f2bf(v[j]);
    }
    __syncthreads();
    // GEMM tail: all 4 waves active at every level
    int q = lane >> 4, m = lane & 15;
    const int* dcl = dcnt + cNOFF[l];
    ushortT* f1bfl = f1bf + cF1OFF[l];
    auto do_task = [&](int task, const uint4* wf) {
        int g = task / numN;               // node group 0/1
        int w = task - g * numN;           // col group
        f32x4 acc = (f32x4){0.f, 0.f, 0.f, 0.f};
#pragma unroll
        for (int st = 0; st < 4; st++) {
            bf16x8 a = *(const bf16x8*)&Sbf[(16 * g + m) * 136 + st * 32 + q * 8];
            bf16x8 bw = __builtin_bit_cast(bf16x8, wf[st]);
            acc = __builtin_amdgcn_mfma_f32_16x16x32_bf16(a, bw, acc, 0, 0, 0);
        }
        int ch = w * 16 + m;
        float rv = RootA.p[l][ch], bv = BiasA.p[l][ch];
#pragma unroll
        for (int rr = 0; rr < 4; rr++) {
            int row = 16 * g + q * 4 + rr;
            if (row < nn) {
                int gnode = node0 + row;
                int dv = dcl[gnode];
                float d = (float)(dv > 1 ? dv : 1);
                float o = acc[rr] / d + x[gnode] * rv + bv;
                f1bfl[(size_t)gnode * C1 + ch] = f2bf(fmaxf(o, 0.f));
            }
        }
    };
    do_task(wv, wfrag0);                   // l0: tasks 0..3; l>0: tasks 0..3 then 4..7
    if (nTask == 8) do_task(wv + 4, wfrag1);
}

// ---- async A-tile stage, QUARTER per wave: each wave issues NC/4 chunks per tile.
// Correctness: the block __syncthreads() after staging drains EVERY wave's own vmcnt
// (compiler emits vmcnt(0) before s_barrier), so after the barrier both tiles' LDS
// is fully populated. 4x fewer issues than the old all-waves-redundant scheme.
template<int CIN>
__device__ __forceinline__ void stage_issue_q(const ushortT* __restrict__ f1bfl, int srcx,
                                              ushortT* lregion, int lane, int wv) {
    const int NC = CIN / 8;               // 16B chunks per row (8 or 4)
    const int Q = (NC >= 4) ? NC / 4 : 1; // chunks this wave issues (2 or 1)
#pragma unroll
    for (int ii = 0; ii < Q; ii++) {
        int i = wv * Q + ii;
        int s = i * 64 + lane;
        int row = s / NC;
        int cp = s & (NC - 1);
        int chunk = cp ^ (row & (NC - 1));
        int src = __shfl(srcx, row, 64);
        const ushortT* gp = f1bfl + (size_t)src * CIN + chunk * 8;
        __builtin_amdgcn_global_load_lds(
            (const __attribute__((address_space(1))) void*)gp,
            (__attribute__((address_space(3))) void*)(lregion + (size_t)i * 512),
            16, 0, 0);
    }
}

// ---- read staged A-frags (same XOR) -> registers ------------------------------------
template<int CIN>
__device__ __forceinline__ void read_ahr(const ushortT* st, bf16x8 (&ahr)[4][CIN / 32],
                                         int q, int m) {
    const int NC = CIN / 8;
#pragma unroll
    for (int mt = 0; mt < 4; mt++) {
        int row = 16 * mt + m;
#pragma unroll
        for (int s = 0; s < CIN / 32; s++) {
            int chunk = s * 4 + q;
            int cp = chunk ^ (row & (NC - 1));
            ahr[mt][s] = *(const bf16x8*)&st[(size_t)row * NC * 8 + cp * 8];
        }
    }
}

// ---- Conv B tile compute: MFMA -> LDS tile assembly -> full-line dst-order store ----
template<int CIN>
__device__ __forceinline__ void conv_b_tile_compute(
    const uint4* __restrict__ whiL, __half* __restrict__ pout,
    bf16x8 (&ahr)[4][CIN / 32], const float* __restrict__ wxy,
    const float* __restrict__ fzp, const int* __restrict__ pd, int valid,
    int cell, int lane, int wv, __half* __restrict__ outS) {
    const int T = CIN / 32;
    int q = lane >> 4, m = lane & 15;
    int cx = cell >> 4, cy = (cell >> 2) & 3, cz = cell & 3;
    float fzr[16];
#pragma unroll
    for (int mt = 0; mt < 4; mt++)
#pragma unroll
        for (int rr = 0; rr < 4; rr++)
            fzr[mt * 4 + rr] = fzp[16 * mt + q * 4 + rr];

    uint4 wb[2][2 * T];
    auto loadw = [&](int xy, uint4* dst) {
        int bx = xy & 1, by = xy >> 1;
        int s0 = (cx + bx) * 25 + (cy + by) * 5 + cz;
#pragma unroll
        for (int st = 0; st < T; st++) {
            dst[st]     = whiL[((size_t)(s0 * T + st) * 4 + wv) * 64 + lane];
            dst[T + st] = whiL[((size_t)((s0 + 1) * T + st) * 4 + wv) * 64 + lane];
        }
    };
    loadw(0, wb[0]);

    f32x4 acc[4];
#pragma unroll
    for (int mt = 0; mt < 4; mt++) acc[mt] = (f32x4){0.f, 0.f, 0.f, 0.f};

#pragma unroll
    for (int xy = 0; xy < 4; xy++) {
        uint4* cur = wb[xy & 1];
        if (xy < 3) loadw(xy + 1, wb[(xy + 1) & 1]);
        f32x4 C0[4], C1[4];
#pragma unroll
        for (int mt = 0; mt < 4; mt++) {
            C0[mt] = (f32x4){0.f, 0.f, 0.f, 0.f};
            C1[mt] = (f32x4){0.f, 0.f, 0.f, 0.f};
        }
#pragma unroll
        for (int st = 0; st < T; st++) {
            bf16x8 b0 = __builtin_bit_cast(bf16x8, cur[st]);
            bf16x8 b1 = __builtin_bit_cast(bf16x8, cur[T + st]);
#pragma unroll
            for (int mt = 0; mt < 4; mt++) {
                C0[mt] = __builtin_amdgcn_mfma_f32_16x16x32_bf16(ahr[mt][st], b0, C0[mt], 0, 0, 0);
                C1[mt] = __builtin_amdgcn_mfma_f32_16x16x32_bf16(ahr[mt][st], b1, C1[mt], 0, 0, 0);
            }
        }
        const float* wrow = &wxy[xy * 64];
#pragma unroll
        for (int mt = 0; mt < 4; mt++)
#pragma unroll
            for (int rr = 0; rr < 4; rr++) {
                float wxyv = wrow[16 * mt + q * 4 + rr];   // LDS broadcast (4 addrs/wave)
                float dlt = C1[mt][rr] - C0[mt][rr];
                float tt = fmaf(fzr[mt * 4 + rr], dlt, C0[mt][rr]);
                acc[mt][rr] = fmaf(wxyv, tt, acc[mt][rr]);
            }
    }
    // assemble output tile in LDS (wave writes its 16-col slice)
#pragma unroll
    for (int mt = 0; mt < 4; mt++)
#pragma unroll
        for (int rr = 0; rr < 4; rr++) {
            int row = 16 * mt + q * 4 + rr;
            outS[row * 68 + 16 * wv + m] = __float2half(acc[mt][rr]);
        }
    __syncthreads();
    // cooperative full-line scatter: 8 lanes x 16B = one 128B row at pd[row]
    int t = (wv << 6) | lane;
#pragma unroll
    for (int p = 0; p < 2; p++) {
        int row = p * 32 + (t >> 3);
        int part = t & 7;
        if (row < valid) {
            uint4 vv = *(const uint4*)&outS[row * 68 + part * 8];
            *(uint4*)&pout[(size_t)pd[row] * 64 + part * 8] = vv;
        }
    }
    __syncthreads();   // outS reusable for next tile
}

// ---- conv B pair: quarter-split staging, one barrier populates both tiles' LDS ------
template<int CIN>
__device__ __forceinline__ void conv_b_pair(
    const ushortT* __restrict__ f1bfl, const int4* __restrict__ cbl,
    const uint4* __restrict__ whiL, __half* __restrict__ pout,
    int d0, int d1, int tb0, int tb1, int lane, int wv,
    ushortT* stage0, ushortT* stage1, __half* __restrict__ outS,
    float* __restrict__ wxy0, float* __restrict__ fz0, int* __restrict__ pd0,
    float* __restrict__ wxy1, float* __restrict__ fz1, int* __restrict__ pd1) {
    const int T = CIN / 32;
    int q = lane >> 4, m = lane & 15;
    bool has1 = d1 >= 0;
    int cell0 = d0 & 63, v0 = d0 >> 8;
    int cell1 = has1 ? (d1 & 63) : 0, v1 = has1 ? (d1 >> 8) : 0;

    int4 r0, r1;
    if (lane < v0) r0 = cbl[tb0 + lane]; else { r0.x = 0; r0.y = 0; r0.z = 0; r0.w = 0; }
    if (lane < v1) r1 = cbl[tb1 + lane]; else { r1.x = 0; r1.y = 0; r1.z = 0; r1.w = 0; }

    {
        unsigned int uz = (unsigned int)r0.z;
        float fx = h2f_lo(uz), fy = h2f_hi(uz);
        float gx = 1.f - fx, gy = 1.f - fy;
        wxy0[0 * 64 + lane] = gx * gy;
        wxy0[1 * 64 + lane] = fx * gy;
        wxy0[2 * 64 + lane] = gx * fy;
        wxy0[3 * 64 + lane] = fx * fy;
        fz0[lane] = h2f_lo((unsigned int)r0.w);
        pd0[lane] = r0.y;
    }
    {
        unsigned int uz = (unsigned int)r1.z;
        float fx = h2f_lo(uz), fy = h2f_hi(uz);
        float gx = 1.f - fx, gy = 1.f - fy;
        wxy1[0 * 64 + lane] = gx * gy;
        wxy1[1 * 64 + lane] = fx * gy;
        wxy1[2 * 64 + lane] = gx * fy;
        wxy1[3 * 64 + lane] = fx * fy;
        fz1[lane] = h2f_lo((unsigned int)r1.w);
        pd1[lane] = r1.y;
    }

    // quarter-split stage issue: each wave issues NC/4 chunks per tile (4x fewer)
    stage_issue_q<CIN>(f1bfl, r0.x, stage0, lane, wv);
    if (has1) stage_issue_q<CIN>(f1bfl, r1.x, stage1, lane, wv);

    // one barrier: compiler drains each wave's vmcnt before s_barrier, so after
    // this ALL waves' stage quarters (both tiles) are in LDS; wxy/fz/pd also visible.
    __syncthreads();

    bf16x8 ahr[4][T];
    read_ahr<CIN>(stage0, ahr, q, m);
    conv_b_tile_compute<CIN>(whiL, pout, ahr, wxy0, fz0, pd0, v0, cell0, lane, wv, outS);

    if (has1) {
        read_ahr<CIN>(stage1, ahr, q, m);
        conv_b_tile_compute<CIN>(whiL, pout, ahr, wxy1, fz1, pd1, v1, cell1, lane, wv, outS);
    }
}

// ---- merged: rgemm (b<609) | conv B tile pairs — independent outputs f2 / Ph --------
__launch_bounds__(256, 3)
__global__ void conv_brg(const ushortT* __restrict__ f1bf, const int4* __restrict__ cbrec,
                         const uint4* __restrict__ whi, const int* __restrict__ cot,
                         __half* __restrict__ Ph,
                         const uint4* __restrict__ rb, float* __restrict__ f2) {
    __shared__ __align__(16) ushortT stageS[2][4096];  // 2 tiles x 8KB (worst CIN=64)
    __shared__ __align__(16) __half outS[64 * 68];     // 8704B output assembly tile
    __shared__ float wxyS[2][256];
    __shared__ float fzS[2][64];
    __shared__ int pdS[2][64];
    int t = threadIdx.x;
    int wv = t >> 6, lane = t & 63;
    int blk = blockIdx.x;
    if (blk < 609) {
        // ---- R-gemm: f2 = f1bf @ rootb (independent of conv_b; overlaps it) ----
        int b = blk;
        int l = (b >= cRGB[4]) ? 4 : (b >= cRGB[3]) ? 3 : (b >= cRGB[2]) ? 2 : (b >= cRGB[1]) ? 1 : 0;
        int node0 = (b - cRGB[l]) * 64;
        int n = cN[l];
        int nn = n - node0; if (nn > 64) nn = 64;
        int q = lane >> 4, m = lane & 15;
        const int CIN = l ? 64 : 32;
        const int T = l ? 2 : 1;
        const ushortT* fl = f1bf + cF1OFF[l];
        const uint4* rbl = rb + cRBOFF[l];
        f32x4 C[4];
#pragma unroll
        for (int mt = 0; mt < 4; mt++) C[mt] = (f32x4){0.f, 0.f, 0.f, 0.f};
        for (int st = 0; st < T; st++) {
            bf16x8 bh = __builtin_bit_cast(bf16x8, rbl[(st * 4 + wv) * 64 + lane]);
#pragma unroll
            for (int mt = 0; mt < 4; mt++) {
                int row = 16 * mt + m;
                int nr = node0 + row; if (nr > n - 1) nr = n - 1;
                bf16x8 a = *(const bf16x8*)&fl[(size_t)nr * CIN + st * 32 + q * 8];
                C[mt] = __builtin_amdgcn_mfma_f32_16x16x32_bf16(a, bh, C[mt], 0, 0, 0);
            }
        }
#pragma unroll
        for (int mt = 0; mt < 4; mt++)
#pragma unroll
            for (int rr = 0; rr < 4; rr++) {
                int row = 16 * mt + q * 4 + rr;
                if (row < nn)
                    f2[(size_t)(cNOFF[l] + node0 + row) * 64 + 16 * wv + m] = C[mt][rr];
            }
        return;
    }
    // ---- conv B pair path ----
    int b = blk - 609;
    int l = (b >= cPAIR[4]) ? 4 : (b >= cPAIR[3]) ? 3 : (b >= cPAIR[2]) ? 2 : (b >= cPAIR[1]) ? 1 : 0;
    int p = b - cPAIR[l];
    int t0 = 2 * p, t1 = t0 + 1;
    const int* cotl = cot + cTILEOFF[l];
    int d0 = cotl[t0];
    int d1 = (t1 < cMT[l]) ? cotl[t1] : -1;
    if (d0 < 0) return;                    // block-uniform
    int tb0 = t0 * 64, tb1 = t1 * 64;
    if (l == 0)
        conv_b_pair<32>(f1bf, cbrec, whi, Ph, d0, d1, tb0, tb1, lane, wv,
                        stageS[0], stageS[1], outS,
                        wxyS[0], fzS[0], pdS[0], wxyS[1], fzS[1], pdS[1]);
    else
        conv_b_pair<64>(f1bf + cF1OFF[l], cbrec + cSEOFF[l], whi + cWOFF[l],
                        Ph + (size_t)cEOFF[l] * 64, d0, d1, tb0, tb1, lane, wv,
                        stageS[0], stageS[1], outS,
                        wxyS[0], fzS[0], pdS[0], wxyS[1], fzS[1], pdS[1]);
}

// ---- fused node epilogue + readout: 8-node windows, 2-deep vectorized Ph stream -----
__launch_bounds__(256)
__global__ void node_read(const __half* __restrict__ Ph,
                          const int* __restrict__ dbase, const int* __restrict__ boff,
                          const int* __restrict__ dcnt, P5f BiasB, P5i Batch,
                          const float* __restrict__ f2,
                          float* __restrict__ hsum, float* __restrict__ gcnt) {
    const int RC[6] = {0, 2500, 3750, 4375, 4688, 4845};   // ceil(N/8) prefix
    int t = threadIdx.x;
    int lane = t & 63;
    int w = blockIdx.x * 4 + (t >> 6);
    if (w >= 4845) return;
    int l = (w >= RC[4]) ? 4 : (w >= RC[3]) ? 3 : (w >= RC[2]) ? 2 : (w >= RC[1]) ? 1 : 0;
    int base = (w - RC[l]) * 8;
    int Nl = cN[l];
    int nn = Nl - base; if (nn > 8) nn = 8;
    const __half* PhL = Ph + (size_t)cEOFF[l] * 64;
    const float* f2b = f2 + (size_t)(cNOFF[l] + base) * 64;
    int c4 = (lane & 15) * 4;              // this lane's channel quad
    int rp = lane >> 4;                    // row parity 0..3
    float4 bias4 = *(const float4*)&BiasB.p[l][c4];
    // lane-parallel metadata load for the window's 8 nodes, broadcast via shfl
    int myStart = 0, myDeg = 0, myG = 0;
    if (lane < nn) {
        int node = base + lane;
        myStart = dbase[cNOFF[l] + node] + boff[cNBLKOFF[l] + (node >> 8)];
        myDeg = dcnt[cNOFF[l] + node];
        myG = Batch.p[l][node];
    }
    int curg = -1;
    float h0 = 0.f, h1 = 0.f, h2 = 0.f, h3 = 0.f;   // run accumulator (channel quad)
    int crun = 0;
    for (int j = 0; j < nn; j++) {
        int start = __shfl(myStart, j, 64);
        int deg = __shfl(myDeg, j, 64);
        int g = __shfl(myG, j, 64);
        float a0 = 0.f, a1 = 0.f, a2 = 0.f, a3 = 0.f;
        float b0 = 0.f, b1 = 0.f, b2 = 0.f, b3 = 0.f;
        int k = 0;
        for (; k + 8 <= deg; k += 8) {      // two independent 512B wave-loads in flight
            uint2 v = *(const uint2*)(PhL + (size_t)(start + k) * 64 + lane * 4);
            uint2 u = *(const uint2*)(PhL + (size_t)(start + k + 4) * 64 + lane * 4);
            a0 += h2f_lo(v.x); a1 += h2f_hi(v.x);
            a2 += h2f_lo(v.y); a3 += h2f_hi(v.y);
            b0 += h2f_lo(u.x); b1 += h2f_hi(u.x);
            b2 += h2f_lo(u.y); b3 += h2f_hi(u.y);
        }
        for (; k + 4 <= deg; k += 4) {      // 4 rows = 512B per wave-load
            uint2 v = *(const uint2*)(PhL + (size_t)(start + k) * 64 + lane * 4);
            a0 += h2f_lo(v.x); a1 += h2f_hi(v.x);
            a2 += h2f_lo(v.y); a3 += h2f_hi(v.y);
        }
        if (k < deg && k + rp < deg) {      // tail rows, same lane->channel mapping
            uint2 v = *(const uint2*)(PhL + (size_t)(start + k) * 64 + lane * 4);
            a0 += h2f_lo(v.x); a1 += h2f_hi(v.x);
            a2 += h2f_lo(v.y); a3 += h2f_hi(v.y);
        }
        a0 += b0; a1 += b1; a2 += b2; a3 += b3;
        // merge the 4 row-parities: lanes L, L^16, L^32, L^48 share a channel quad
        a0 += __shfl_xor(a0, 16, 64); a1 += __shfl_xor(a1, 16, 64);
        a2 += __shfl_xor(a2, 16, 64); a3 += __shfl_xor(a3, 16, 64);
        a0 += __shfl_xor(a0, 32, 64); a1 += __shfl_xor(a1, 32, 64);
        a2 += __shfl_xor(a2, 32, 64); a3 += __shfl_xor(a3, 32, 64);
        float dinv = 1.f / (float)(deg > 1 ? deg : 1);
        float4 fr = *(const float4*)&f2b[(size_t)j * 64 + c4];
        float s0 = fmaxf(a0 * dinv + fr.x + bias4.x, 0.f);
        float s1 = fmaxf(a1 * dinv + fr.y + bias4.y, 0.f);
        float s2 = fmaxf(a2 * dinv + fr.z + bias4.z, 0.f);
        float s3 = fmaxf(a3 * dinv + fr.w + bias4.w, 0.f);
        if (g != curg) {
            if (curg >= 0) {
                if (lane < 16) {
                    float* hp = &hsum[curg * 320 + l * 64 + c4];
                    atomicAdd(hp + 0, h0); atomicAdd(hp + 1, h1);
                    atomicAdd(hp + 2, h2); atomicAdd(hp + 3, h3);
                }
                if (lane == 0) atomicAdd(&gcnt[l * 64 + curg], (float)crun);
            }
            curg = g; h0 = h1 = h2 = h3 = 0.f; crun = 0;
        }
        h0 += s0; h1 += s1; h2 += s2; h3 += s3;
        crun++;
    }
    if (curg >= 0) {
        if (lane < 16) {
            float* hp = &hsum[curg * 320 + l * 64 + c4];
            atomicAdd(hp + 0, h0); atomicAdd(hp + 1, h1);
            atomicAdd(hp + 2, h2); atomicAdd(hp + 3, h3);
        }
        if (lane == 0) atomicAdd(&gcnt[l * 64 + curg], (float)crun);
    }
}

// ---------------- FC + log_softmax: one block per graph ----------------
__global__ void fc_kernel(const float* __restrict__ hsum, const float* __restrict__ gcnt,
                          const float* __restrict__ fcw, const float* __restrict__ fcb,
                          float* __restrict__ out) {
    int g = blockIdx.x;
    int lane = threadIdx.x;  // 64
    float partial[10];
#pragma unroll
    for (int t = 0; t < 10; t++) partial[t] = 0.f;
#pragma unroll
    for (int k = 0; k < 5; k++) {
        int j = k * 64 + lane;
        float c = fmaxf(gcnt[k * 64 + g], 1.f);
        float h = hsum[g * 320 + j] / c;
        const float* fw = fcw + j * 10;
#pragma unroll
        for (int t = 0; t < 10; t++) partial[t] = fmaf(h, fw[t], partial[t]);
    }
#pragma unroll
    for (int off = 32; off >= 1; off >>= 1)
#pragma unroll
        for (int t = 0; t < 10; t++) partial[t] += __shfl_xor(partial[t], off, 64);
    if (lane == 0) {
        float logit[10];
#pragma unroll
        for (int t = 0; t < 10; t++) logit[t] = partial[t] + fcb[t];
        float m = logit[0];
#pragma unroll
        for (int t = 1; t < 10; t++) m = fmaxf(m, logit[t]);
        float sum = 0.f;
#pragma unroll
        for (int t = 0; t < 10; t++) sum += expf(logit[t] - m);
        float lse = m + logf(sum);
#pragma unroll
        for (int t = 0; t < 10; t++) out[g * 10 + t] = logit[t] - lse;
    }
}

extern "C" void kernel_launch(void* const* d_in, const int* in_sizes, int n_in,
                              void* d_out, int out_size, void* d_ws, size_t ws_size,
                              hipStream_t stream) {
    int* wsI = (int*)d_ws;
    int*   dcnt  = wsI;                          // 38750
    int*   rank  = dcnt + 38750;                 // 38750
    float* hsum  = (float*)(rank + 38750);       // 20480  (hsum[g*320 + l*64 + lane])
    float* gcnt  = hsum + 20480;                 // 320
    float* f2    = gcnt + 320;                   // 2,480,000 (R from rgemm; read-only in node_read)
    int*   dbase = (int*)(f2 + 2480000);         // 38750
    int*   bsum  = dbase + 38750;                // 160
    int*   boff  = bsum + 160;                   // 160
    int*   cpos  = boff + 160;                   // 620000 (unused after dst-order Ph)
    int*   bb    = cpos + 620000;                // 155136
    int*   csPad = bb + 155136;                  // 320
    int*   cellTot = csPad + 320;                // 320
    int*   cot   = cellTot + 320;                // 10008
    int4*  cbrec = (int4*)(((size_t)(cot + 10008) + 15) & ~(size_t)15);   // 640512 recs
    int4*  darec = cbrec + 640512;               // 620000 recs
    ushortT* f1bf = (ushortT*)(darec + 620000);  // 1,840,000 ushorts
    uint4* whi   = (uint4*)(((size_t)(f1bf + 1840000) + 15) & ~(size_t)15);  // 288000
    uint4* rbsw  = whi + 288000;                 // 2304
    uint4* wasw  = rbsw + 2304;                  // 4608
    __half* Ph   = (__half*)(wasw + 4608);       // 620000 rows of 64 (dst-ordered per level)

    hipMemsetAsync(dcnt, 0, (size_t)(38750 * 2 + 20480 + 320) * sizeof(int), stream);

    P5f PS, X, WA, RootA, BiasA, WB, RootB, BiasB;
    P5i EI, Batch;
    for (int l = 0; l < 5; l++) {
        const int b = l * 10;
        X.p[l]     = (const float*)d_in[b + 0];
        PS.p[l]    = (const float*)d_in[b + 1];
        EI.p[l]    = (const int*)d_in[b + 2];
        Batch.p[l] = (const int*)d_in[b + 3];
        WA.p[l]    = (const float*)d_in[b + 4];
        RootA.p[l] = (const float*)d_in[b + 5];
        BiasA.p[l] = (const float*)d_in[b + 6];
        WB.p[l]    = (const float*)d_in[b + 7];
        RootB.p[l] = (const float*)d_in[b + 8];
        BiasB.p[l] = (const float*)d_in[b + 9];
    }

    // prep: hist + weight-swizzle fused (wswz independent, hides under hist)
    k_hist_wswz<<<3576, 256, 0, stream>>>(PS, EI, dcnt, bb, WB, RootB, WA,
                                          whi, rbsw, wasw);
    k_scan1<<<234, 256, 0, stream>>>(bb, cellTot, dcnt, dbase, bsum);
    k_scan2<<<10, 64, 0, stream>>>(cellTot, csPad, cot, bsum, boff);
    k_scatter<<<2424, 256, 0, stream>>>(PS, EI, bb, csPad, dbase, boff, rank,
                                        cbrec, darec);

    // conv A (all levels, 32-node blocks, pipelined staging) -> f1bf
    conv_a_fused<<<1214, 256, 0, stream>>>(X, RootA, BiasA, darec, wasw,
                                           dbase, boff, dcnt, f1bf);

    // rgemm + conv B fused (quarter-split staging; independent outputs f2 / Ph)
    conv_brg<<<5614, 256, 0, stream>>>(f1bf, cbrec, whi, cot, Ph, rbsw, f2);

    // fused node epilogue + readout: 2-deep vectorized Ph stream -> run atomics
    node_read<<<1212, 256, 0, stream>>>(Ph, dbase, boff, dcnt, BiasB, Batch, f2,
                                        hsum, gcnt);

    // FC + log_softmax
    fc_kernel<<<64, 64, 0, stream>>>(hsum, gcnt, (const float*)d_in[50], (const float*)d_in[51],
                                     (float*)d_out);
}